// Round 10
// baseline (567.029 us; speedup 1.0000x reference)
//
#include <hip/hip_runtime.h>
#include <hip/hip_bf16.h>

#define DD 1024
#define HH 4096
#define EE 8
#define NN 4096   // B*T tokens

typedef __attribute__((ext_vector_type(8))) short bf16x8;
typedef __attribute__((ext_vector_type(4))) float f32x4;
typedef __attribute__((ext_vector_type(16))) float f32x16;
typedef __attribute__((ext_vector_type(8))) unsigned short u16x8;

#define AS1P(p) ((__attribute__((address_space(1))) void*)(unsigned long long)(const void*)(p))
#define AS3P(p) ((__attribute__((address_space(3))) void*)(unsigned int)(unsigned long long)(const void*)(p))

__device__ inline f32x16 mfma32(bf16x8 a, bf16x8 b, f32x16 c) {
    return __builtin_amdgcn_mfma_f32_32x32x16_bf16(a, b, c, 0, 0, 0);
}

// ---------------------------------------------------------------------------
// Fused transpose + fp32->bf16 for W1, W2 (eg-scaled, eb@W bias) and Wo.
// z = 0..7: W1, 8..15: W2, 16..23: Wo.
// ---------------------------------------------------------------------------
__global__ __launch_bounds__(256) void transpose_all(
    const float* __restrict__ W1, const float* __restrict__ W2,
    const float* __restrict__ Wo, const float* __restrict__ eg,
    const float* __restrict__ eb, __hip_bfloat16* __restrict__ W1T,
    __hip_bfloat16* __restrict__ W2T, __hip_bfloat16* __restrict__ WoT,
    float* __restrict__ b1a, float* __restrict__ b2a)
{
    __shared__ float tile[64][66];
    __shared__ float sg[64], sb[64];
    const int z   = blockIdx.z;
    const int mat = z >> 3;          // 0:W1 1:W2 2:Wo
    const int e   = z & 7;
    const int R   = (mat == 2) ? HH : DD;
    const int C   = (mat == 2) ? DD : HH;
    const int cT  = C >> 6;
    const int bx  = blockIdx.x;      // 0..1023
    const int c0  = (bx % cT) * 64;
    const int r0  = (bx / cT) * 64;
    const float* src = (mat == 0) ? W1 : (mat == 1) ? W2 : Wo;
    __hip_bfloat16* dst = (mat == 0) ? W1T : (mat == 1) ? W2T : WoT;
    const bool SC = (mat < 2);
    float* badd = (mat == 0) ? b1a : b2a;
    const int t = threadIdx.x;

    const float* s = src + (size_t)e * R * C + (size_t)r0 * C + c0;
    if (SC && t < 64) {
        sg[t] = eg[e * DD + r0 + t];
        sb[t] = eb[e * DD + r0 + t];
    }
    #pragma unroll
    for (int i = 0; i < 4; i++) {
        const int rr = i * 16 + (t >> 4);
        const int cc = (t & 15) * 4;
        const float4 v = *(const float4*)(s + (size_t)rr * C + cc);
        tile[rr][cc] = v.x; tile[rr][cc + 1] = v.y;
        tile[rr][cc + 2] = v.z; tile[rr][cc + 3] = v.w;
    }
    __syncthreads();

    __hip_bfloat16* d = dst + (size_t)e * R * C + (size_t)c0 * R + r0;
    #pragma unroll
    for (int i = 0; i < 2; i++) {
        const int id = t + 256 * i;
        const int cc = id >> 3;
        const int rb = (id & 7) * 8;
        union { u16x8 v; __hip_bfloat16 h[8]; } u;
        #pragma unroll
        for (int j = 0; j < 8; j++) {
            float v = tile[rb + j][cc];
            if (SC) v *= sg[rb + j];
            u.h[j] = __float2bfloat16(v);
        }
        *(u16x8*)(d + (size_t)cc * R + rb) = u.v;
    }
    if (SC && t < 64) {
        float sum = 0.f;
        #pragma unroll
        for (int rr = 0; rr < 64; rr++) sum += sb[rr] * tile[rr][t];
        atomicAdd(&badd[e * C + c0 + t], sum);
    }
}

// ---------------------------------------------------------------------------
// Per-token: LN1 -> router -> top2+softmax -> scatter; store LN2-normalized
// token as bf16 (eg/eb folded into weights); record slots per token.
// ---------------------------------------------------------------------------
__global__ __launch_bounds__(256) void token_kernel(
    const float* __restrict__ x, const float* __restrict__ lng, const float* __restrict__ lnb,
    const float* __restrict__ rw, __hip_bfloat16* __restrict__ xhat,
    int* __restrict__ counts, int* __restrict__ lists, float* __restrict__ gates,
    int* __restrict__ pairIdx)
{
    const int i = blockIdx.x;
    const int t = threadIdx.x;
    __shared__ float sA[256], sB[256];
    __shared__ float slog[32];

    float4 xv = ((const float4*)(x + (size_t)i * DD))[t];
    float s1 = xv.x + xv.y + xv.z + xv.w;
    float s2 = xv.x * xv.x + xv.y * xv.y + xv.z * xv.z + xv.w * xv.w;
    sA[t] = s1; sB[t] = s2;
    __syncthreads();
    for (int s = 128; s > 0; s >>= 1) {
        if (t < s) { sA[t] += sA[t + s]; sB[t] += sB[t + s]; }
        __syncthreads();
    }
    const float mu  = sA[0] * (1.0f / DD);
    const float var = sB[0] * (1.0f / DD) - mu * mu;
    const float rstd = rsqrtf(var + 1e-5f);
    __syncthreads();

    float4 gv = ((const float4*)lng)[t];
    float4 bv = ((const float4*)lnb)[t];
    float xf[4];
    xf[0] = (xv.x - mu) * rstd * gv.x + bv.x;
    xf[1] = (xv.y - mu) * rstd * gv.y + bv.y;
    xf[2] = (xv.z - mu) * rstd * gv.z + bv.z;
    xf[3] = (xv.w - mu) * rstd * gv.w + bv.w;

    float lp[8];
    #pragma unroll
    for (int e = 0; e < 8; e++) lp[e] = 0.f;
    {
        const float4* r4 = (const float4*)(rw + (size_t)(t * 4) * EE);
        #pragma unroll
        for (int j = 0; j < 4; j++) {
            float4 ra = r4[j * 2], rb = r4[j * 2 + 1];
            lp[0] += xf[j] * ra.x; lp[1] += xf[j] * ra.y;
            lp[2] += xf[j] * ra.z; lp[3] += xf[j] * ra.w;
            lp[4] += xf[j] * rb.x; lp[5] += xf[j] * rb.y;
            lp[6] += xf[j] * rb.z; lp[7] += xf[j] * rb.w;
        }
    }
    const int lane = t & 63, wid = t >> 6;
    #pragma unroll
    for (int e = 0; e < 8; e++) {
        float v = lp[e];
        #pragma unroll
        for (int o = 32; o > 0; o >>= 1) v += __shfl_down(v, o, 64);
        if (lane == 0) slog[e * 4 + wid] = v;
    }

    s1 = xf[0] + xf[1] + xf[2] + xf[3];
    s2 = xf[0] * xf[0] + xf[1] * xf[1] + xf[2] * xf[2] + xf[3] * xf[3];
    sA[t] = s1; sB[t] = s2;
    __syncthreads();
    for (int s = 128; s > 0; s >>= 1) {
        if (t < s) { sA[t] += sA[t + s]; sB[t] += sB[t + s]; }
        __syncthreads();
    }
    const float mu2  = sA[0] * (1.0f / DD);
    const float var2 = sB[0] * (1.0f / DD) - mu2 * mu2;
    const float rstd2 = rsqrtf(var2 + 1e-5f);

    union { ushort4 v; __hip_bfloat16 h[4]; } u;
    u.h[0] = __float2bfloat16((xf[0] - mu2) * rstd2);
    u.h[1] = __float2bfloat16((xf[1] - mu2) * rstd2);
    u.h[2] = __float2bfloat16((xf[2] - mu2) * rstd2);
    u.h[3] = __float2bfloat16((xf[3] - mu2) * rstd2);
    ((ushort4*)(xhat + (size_t)i * DD))[t] = u.v;

    if (t == 0) {
        float lg[8];
        #pragma unroll
        for (int e = 0; e < 8; e++)
            lg[e] = slog[e * 4] + slog[e * 4 + 1] + slog[e * 4 + 2] + slog[e * 4 + 3];
        int i0 = 0;
        #pragma unroll
        for (int e = 1; e < 8; e++) if (lg[e] > lg[i0]) i0 = e;
        int i1 = (i0 == 0) ? 1 : 0;
        #pragma unroll
        for (int e = 0; e < 8; e++) { if (e != i0 && lg[e] > lg[i1]) i1 = e; }
        const float ex = __expf(lg[i1] - lg[i0]);
        const float g0 = 1.f / (1.f + ex);
        const float g1 = ex / (1.f + ex);
        int p0 = atomicAdd(&counts[i0], 1);
        lists[i0 * NN + p0] = i; gates[i0 * NN + p0] = g0;
        int p1 = atomicAdd(&counts[i1], 1);
        lists[i1 * NN + p1] = i; gates[i1 * NN + p1] = g1;
        pairIdx[2 * i]     = i0 * NN + p0;
        pairIdx[2 * i + 1] = i1 * NN + p1;
    }
}

// ---------------------------------------------------------------------------
// GEMM1 v9b: 32x32x16 MFMA. 4 waves 2Mx2N, BM=128, h-panel=64 x {W1,W2},
// BK=32 (row pitch 32 elems!), 32KB LDS. FIX vs v9: staging dest offsets are
// i*2048 + w*512 (64 rows = 2048 elems at pitch 32; v9 used the old pitch-64
// strides i*4096 + w*1024 and overflowed the buffers).
// ---------------------------------------------------------------------------
__global__ __launch_bounds__(256, 3) void gemm1_kernel(
    const __hip_bfloat16* __restrict__ xhat,
    const __hip_bfloat16* __restrict__ w1t, const __hip_bfloat16* __restrict__ w2t,
    const float* __restrict__ b1, const float* __restrict__ b2,
    const float* __restrict__ b1a, const float* __restrict__ b2a,
    const int* __restrict__ counts, const int* __restrict__ lists,
    __hip_bfloat16* __restrict__ hid)
{
    const int gid  = blockIdx.x;            // 0..8191
    const int xcd  = gid & 7;
    const int rest = gid >> 3;              // 0..1023
    const int m    = rest & 15;
    const int pidx = rest >> 4;             // 0..63
    const int panel = xcd + 8 * pidx;       // 0..511: all m-blocks of panel on one XCD
    const int e   = panel >> 6;
    const int h0  = (panel & 63) * 64;
    const int cnt = counts[e];
    const int m0  = m * 128;
    if (m0 >= cnt) return;
    int base = 0;
    #pragma unroll
    for (int j = 0; j < 8; j++) base += (j < e) ? counts[j] : 0;

    __shared__ __align__(16) __hip_bfloat16 As[2][128 * 32];   // 8KB x2
    __shared__ __align__(16) __hip_bfloat16 Bs[2][128 * 32];   // 8KB x2: rows 0-63 W1, 64-127 W2
    __shared__ int toks[128];

    const int t = threadIdx.x, lane = t & 63, w = t >> 6;
    const int wm = w >> 1, wn = w & 1;      // 2M x 2N
    const int r31 = lane & 31, kg = lane >> 5;
    const int swz = (r31 >> 1) & 3;
    const int cl = (lane & 3) ^ ((lane >> 3) & 3);   // staging inverse-swizzle chunk
    const int koff0 = ((kg)     ^ swz) * 8;          // kk=0 frag chunk (elements)
    const int koff1 = ((2 + kg) ^ swz) * 8;          // kk=1

    if (t < 128) toks[t] = lists[e * NN + min(m0 + t, cnt - 1)];

    f32x16 acc1[2], acc2[2];                // [mt] row-tiles; W1 / W2
    #pragma unroll
    for (int q = 0; q < 2; q++) {
        acc1[q] = (f32x16)(0.f);
        acc2[q] = (f32x16)(0.f);
    }

    __syncthreads();                        // toks visible

    const __hip_bfloat16* pA[2];
    #pragma unroll
    for (int i = 0; i < 2; i++)
        pA[i] = xhat + (size_t)toks[i * 64 + w * 16 + (lane >> 2)] * DD + cl * 8;
    const __hip_bfloat16* pB[2];
    {
        const int brow = h0 + w * 16 + (lane >> 2);
        pB[0] = w1t + ((size_t)e * HH + brow) * DD + cl * 8;
        pB[1] = w2t + ((size_t)e * HH + brow) * DD + cl * 8;
    }

    // frag read offsets (elements), loop-invariant
    int aoff[2];
    #pragma unroll
    for (int mt = 0; mt < 2; mt++) aoff[mt] = (wm * 64 + mt * 32 + r31) * 32;
    const int boff1 = (wn * 32 + r31) * 32;
    const int boff2 = (64 + wn * 32 + r31) * 32;

    auto STAGE = [&](int buf, int ko) {
        #pragma unroll
        for (int i = 0; i < 2; i++)
            __builtin_amdgcn_global_load_lds(AS1P(pA[i] + ko), AS3P(&As[buf][i * 2048 + w * 512]), 16, 0, 0);
        #pragma unroll
        for (int i = 0; i < 2; i++)
            __builtin_amdgcn_global_load_lds(AS1P(pB[i] + ko), AS3P(&Bs[buf][i * 2048 + w * 512]), 16, 0, 0);
    };
    auto COMPUTE = [&](int buf) {
        const __hip_bfloat16* A = As[buf];
        const __hip_bfloat16* B = Bs[buf];
        bf16x8 a[2][2], b1f[2], b2f[2];
        #pragma unroll
        for (int mt = 0; mt < 2; mt++) {
            a[mt][0] = *(const bf16x8*)&A[aoff[mt] + koff0];
            a[mt][1] = *(const bf16x8*)&A[aoff[mt] + koff1];
        }
        b1f[0] = *(const bf16x8*)&B[boff1 + koff0];
        b1f[1] = *(const bf16x8*)&B[boff1 + koff1];
        b2f[0] = *(const bf16x8*)&B[boff2 + koff0];
        b2f[1] = *(const bf16x8*)&B[boff2 + koff1];
        __builtin_amdgcn_s_setprio(1);
        #pragma unroll
        for (int mt = 0; mt < 2; mt++)
            #pragma unroll
            for (int kk = 0; kk < 2; kk++) {
                acc1[mt] = mfma32(a[mt][kk], b1f[kk], acc1[mt]);
                acc2[mt] = mfma32(a[mt][kk], b2f[kk], acc2[mt]);
            }
        __builtin_amdgcn_s_setprio(0);
    };

    STAGE(0, 0);
    __syncthreads();
    int ko = 0;
    #pragma unroll 1
    for (int it = 0; it < 15; ++it) {
        STAGE(1, ko + 32); COMPUTE(0); __syncthreads();
        STAGE(0, ko + 64); COMPUTE(1); __syncthreads();
        ko += 64;
    }
    STAGE(1, 992); COMPUTE(0); __syncthreads();
    COMPUTE(1);

    const int hcol = h0 + wn * 32 + r31;
    const float bb1 = b1[e * HH + hcol] + b1a[e * HH + hcol];
    const float bb2 = b2[e * HH + hcol] + b2a[e * HH + hcol];
    #pragma unroll
    for (int mt = 0; mt < 2; mt++) {
        #pragma unroll
        for (int reg = 0; reg < 16; reg++) {
            const int pos = m0 + wm * 64 + mt * 32 + (reg & 3) + 8 * (reg >> 2) + 4 * kg;
            if (pos < cnt) {
                float x1 = acc1[mt][reg] + bb1;
                float x2 = acc2[mt][reg] + bb2;
                x2 = fminf(fmaxf(x2, -20.f), 20.f);
                float hv = x1 * (x2 / (1.f + __expf(-x2)));
                hv = fminf(fmaxf(hv, -1e4f), 1e4f);
                hid[(size_t)(base + pos) * HH + hcol] = __float2bfloat16(hv);
            }
        }
    }
}

// ---------------------------------------------------------------------------
// GEMM2 v9b: 32x32x16, 4 waves 2Mx2N, BM=128, BN=128 d-cols, BK=32, split-K=4.
// Same staging-offset fix (i*2048 + w*512). Raw partials to P0..P3.
// ---------------------------------------------------------------------------
__global__ __launch_bounds__(256, 3) void gemm2_kernel(
    const __hip_bfloat16* __restrict__ hid, const __hip_bfloat16* __restrict__ wot,
    const int* __restrict__ counts, float* __restrict__ P0, float* __restrict__ P1,
    float* __restrict__ P2, float* __restrict__ P3)
{
    const int gid  = blockIdx.x;            // 0..4095
    const int xcd  = gid & 7;
    const int rest = gid >> 3;              // 0..511
    const int m    = rest & 15;
    const int q    = rest >> 4;             // 0..31
    const int sp   = q & 3;
    const int pidx = q >> 2;                // 0..7
    const int panel = xcd + 8 * pidx;       // 0..63
    const int e   = panel >> 3;
    const int d0  = (panel & 7) * 128;
    const int cnt = counts[e];
    const int m0  = m * 128;
    if (m0 >= cnt) return;
    int base = 0;
    #pragma unroll
    for (int j = 0; j < 8; j++) base += (j < e) ? counts[j] : 0;

    __shared__ __align__(16) __hip_bfloat16 As[2][128 * 32];
    __shared__ __align__(16) __hip_bfloat16 Bs[2][128 * 32];

    const int t = threadIdx.x, lane = t & 63, w = t >> 6;
    const int wm = w >> 1, wn = w & 1;
    const int r31 = lane & 31, kg = lane >> 5;
    const int swz = (r31 >> 1) & 3;
    const int cl = (lane & 3) ^ ((lane >> 3) & 3);
    const int koff0 = ((kg)     ^ swz) * 8;
    const int koff1 = ((2 + kg) ^ swz) * 8;

    f32x16 acc[2][2];                       // [mt][ct]
    #pragma unroll
    for (int a = 0; a < 2; a++) {
        acc[a][0] = (f32x16)(0.f);
        acc[a][1] = (f32x16)(0.f);
    }

    const int kbase = sp * 1024;
    const __hip_bfloat16* pA[2];
    #pragma unroll
    for (int i = 0; i < 2; i++)
        pA[i] = hid + (size_t)(base + min(m0 + i * 64 + w * 16 + (lane >> 2), cnt - 1)) * HH + kbase + cl * 8;
    const __hip_bfloat16* pB[2];
    #pragma unroll
    for (int i = 0; i < 2; i++)
        pB[i] = wot + ((size_t)e * DD + d0 + i * 64 + w * 16 + (lane >> 2)) * HH + kbase + cl * 8;

    int aoff[2];
    #pragma unroll
    for (int mt = 0; mt < 2; mt++) aoff[mt] = (wm * 64 + mt * 32 + r31) * 32;
    int boff[2];
    #pragma unroll
    for (int ct = 0; ct < 2; ct++) boff[ct] = (wn * 64 + ct * 32 + r31) * 32;

    auto STAGE = [&](int buf, int ko) {
        #pragma unroll
        for (int i = 0; i < 2; i++)
            __builtin_amdgcn_global_load_lds(AS1P(pA[i] + ko), AS3P(&As[buf][i * 2048 + w * 512]), 16, 0, 0);
        #pragma unroll
        for (int i = 0; i < 2; i++)
            __builtin_amdgcn_global_load_lds(AS1P(pB[i] + ko), AS3P(&Bs[buf][i * 2048 + w * 512]), 16, 0, 0);
    };
    auto COMPUTE = [&](int buf) {
        const __hip_bfloat16* A = As[buf];
        const __hip_bfloat16* B = Bs[buf];
        bf16x8 a[2][2], b[2][2];
        #pragma unroll
        for (int mt = 0; mt < 2; mt++) {
            a[mt][0] = *(const bf16x8*)&A[aoff[mt] + koff0];
            a[mt][1] = *(const bf16x8*)&A[aoff[mt] + koff1];
        }
        #pragma unroll
        for (int ct = 0; ct < 2; ct++) {
            b[ct][0] = *(const bf16x8*)&B[boff[ct] + koff0];
            b[ct][1] = *(const bf16x8*)&B[boff[ct] + koff1];
        }
        __builtin_amdgcn_s_setprio(1);
        #pragma unroll
        for (int mt = 0; mt < 2; mt++)
            #pragma unroll
            for (int ct = 0; ct < 2; ct++)
                #pragma unroll
                for (int kk = 0; kk < 2; kk++)
                    acc[mt][ct] = mfma32(a[mt][kk], b[ct][kk], acc[mt][ct]);
        __builtin_amdgcn_s_setprio(0);
    };

    STAGE(0, 0);
    __syncthreads();
    int ko = 0;
    #pragma unroll 1
    for (int it = 0; it < 15; ++it) {
        STAGE(1, ko + 32); COMPUTE(0); __syncthreads();
        STAGE(0, ko + 64); COMPUTE(1); __syncthreads();
        ko += 64;
    }
    STAGE(1, 992); COMPUTE(0); __syncthreads();
    COMPUTE(1);

    float* dst = (sp == 0) ? P0 : (sp == 1) ? P1 : (sp == 2) ? P2 : P3;
    #pragma unroll
    for (int mt = 0; mt < 2; mt++) {
        #pragma unroll
        for (int ct = 0; ct < 2; ct++) {
            const int dcol = d0 + wn * 64 + ct * 32 + r31;
            #pragma unroll
            for (int reg = 0; reg < 16; reg++) {
                const int pos = m0 + wm * 64 + mt * 32 + (reg & 3) + 8 * (reg >> 2) + 4 * kg;
                if (pos < cnt)
                    dst[(size_t)(base + pos) * DD + dcol] = acc[mt][ct][reg];
            }
        }
    }
}

// ---------------------------------------------------------------------------
// Combine: out[token] = sum_slots gate * clip(P0+P1+P2+P3 + bo[e], +-1e4)
// ---------------------------------------------------------------------------
__global__ __launch_bounds__(256) void combine_kernel(
    const float* __restrict__ P0, const float* __restrict__ P1,
    const float* __restrict__ P2, const float* __restrict__ P3,
    const float* __restrict__ bo, const int* __restrict__ counts,
    const int* __restrict__ pairIdx, const float* __restrict__ gates,
    float* __restrict__ out)
{
    const int i = blockIdx.x;
    const int t = threadIdx.x;
    const int s0 = pairIdx[2 * i], s1 = pairIdx[2 * i + 1];
    const int e0 = s0 >> 12, p0 = s0 & (NN - 1);
    const int e1 = s1 >> 12, p1 = s1 & (NN - 1);
    int b0 = 0, b1 = 0;
    #pragma unroll
    for (int j = 0; j < 8; j++) {
        const int c = counts[j];
        b0 += (j < e0) ? c : 0;
        b1 += (j < e1) ? c : 0;
    }
    const float g0 = gates[s0], g1 = gates[s1];
    const size_t r0 = (size_t)(b0 + p0) * DD + t * 4;
    const size_t r1 = (size_t)(b1 + p1) * DD + t * 4;
    const float4 a00 = *(const float4*)(P0 + r0), a01 = *(const float4*)(P1 + r0);
    const float4 a02 = *(const float4*)(P2 + r0), a03 = *(const float4*)(P3 + r0);
    const float4 a10 = *(const float4*)(P0 + r1), a11 = *(const float4*)(P1 + r1);
    const float4 a12 = *(const float4*)(P2 + r1), a13 = *(const float4*)(P3 + r1);
    const float4 q0 = ((const float4*)(bo + (size_t)e0 * DD))[t];
    const float4 q1 = ((const float4*)(bo + (size_t)e1 * DD))[t];
    float4 r;
    #pragma unroll
    for (int k = 0; k < 4; k++) {
        float v0 = ((const float*)&a00)[k] + ((const float*)&a01)[k]
                 + ((const float*)&a02)[k] + ((const float*)&a03)[k] + ((const float*)&q0)[k];
        float v1 = ((const float*)&a10)[k] + ((const float*)&a11)[k]
                 + ((const float*)&a12)[k] + ((const float*)&a13)[k] + ((const float*)&q1)[k];
        v0 = fminf(fmaxf(v0, -1e4f), 1e4f);
        v1 = fminf(fmaxf(v1, -1e4f), 1e4f);
        ((float*)&r)[k] = g0 * v0 + g1 * v1;
    }
    ((float4*)(out + (size_t)i * DD))[t] = r;
}

// ---------------------------------------------------------------------------
extern "C" void kernel_launch(void* const* d_in, const int* in_sizes, int n_in,
                              void* d_out, int out_size, void* d_ws, size_t ws_size,
                              hipStream_t stream)
{
    const float* x   = (const float*)d_in[0];
    const float* lng = (const float*)d_in[1];
    const float* lnb = (const float*)d_in[2];
    const float* rw  = (const float*)d_in[3];
    const float* eg  = (const float*)d_in[4];
    const float* eb  = (const float*)d_in[5];
    const float* W1  = (const float*)d_in[6];
    const float* b1  = (const float*)d_in[7];
    const float* W2  = (const float*)d_in[8];
    const float* b2  = (const float*)d_in[9];
    const float* Wo  = (const float*)d_in[10];
    const float* bo  = (const float*)d_in[11];
    float* out = (float*)d_out;

    char* ws = (char*)d_ws;
    const size_t WSZ = (size_t)EE * HH * DD * 2;      // 64MB per weight matrix
    __hip_bfloat16* W1T  = (__hip_bfloat16*)(ws);
    __hip_bfloat16* W2T  = (__hip_bfloat16*)(ws + WSZ);
    __hip_bfloat16* WoT  = (__hip_bfloat16*)(ws + 2 * WSZ);
    __hip_bfloat16* xhat = (__hip_bfloat16*)(ws + 3 * WSZ);
    __hip_bfloat16* hid  = (__hip_bfloat16*)(ws + 3 * WSZ + (size_t)NN * DD * 2);
    char* small = ws + 3 * WSZ + (size_t)NN * DD * 2 + (size_t)2 * NN * HH * 2;
    int*   counts  = (int*)small;
    float* b1a     = (float*)(small + 256);
    float* b2a     = (float*)(small + 256 + 131072);
    int*   lists   = (int*)(small + 256 + 2 * 131072);
    float* gates   = (float*)(small + 256 + 3 * 131072);
    int*   pairIdx = (int*)(small + 256 + 4 * 131072);
    // split-K partials (each 8192x1024 f32 = 32MB): P0/P1 alias W1T, P2/P3 alias
    // W2T — both dead after gemm1, rewritten by transpose_all next call.
    float* P0 = (float*)(ws);
    float* P1 = (float*)(ws + WSZ / 2);
    float* P2 = (float*)(ws + WSZ);
    float* P3 = (float*)(ws + WSZ + WSZ / 2);

    hipMemsetAsync(small, 0, 256 + 2 * 131072, stream);   // counts + b1a + b2a

    transpose_all<<<dim3(1024, 1, 24), 256, 0, stream>>>(
        W1, W2, Wo, eg, eb, W1T, W2T, WoT, b1a, b2a);

    token_kernel<<<NN, 256, 0, stream>>>(x, lng, lnb, rw, xhat, counts, lists, gates, pairIdx);

    gemm1_kernel<<<8192, 256, 0, stream>>>(
        xhat, W1T, W2T, b1, b2, b1a, b2a, counts, lists, hid);
    gemm2_kernel<<<4096, 256, 0, stream>>>(
        hid, WoT, counts, P0, P1, P2, P3);
    combine_kernel<<<NN, 256, 0, stream>>>(P0, P1, P2, P3, bo, counts, pairIdx, gates, out);
}

// Round 11
// 554.327 us; speedup vs baseline: 1.0229x; 1.0229x over previous
//
#include <hip/hip_runtime.h>
#include <hip/hip_bf16.h>

#define DD 1024
#define HH 4096
#define EE 8
#define NN 4096   // B*T tokens

typedef __attribute__((ext_vector_type(8))) short bf16x8;
typedef __attribute__((ext_vector_type(4))) float f32x4;
typedef __attribute__((ext_vector_type(8))) unsigned short u16x8;

#define AS1P(p) ((__attribute__((address_space(1))) void*)(unsigned long long)(const void*)(p))
#define AS3P(p) ((__attribute__((address_space(3))) void*)(unsigned int)(unsigned long long)(const void*)(p))

__device__ inline f32x4 mfma16(bf16x8 a, bf16x8 b, f32x4 c) {
    return __builtin_amdgcn_mfma_f32_16x16x32_bf16(a, b, c, 0, 0, 0);
}

// ---------------------------------------------------------------------------
// Fused transpose + fp32->bf16 for W1, W2 (eg-scaled, eb@W bias) and Wo.
// z = 0..7: W1, 8..15: W2, 16..23: Wo.
// ---------------------------------------------------------------------------
__global__ __launch_bounds__(256) void transpose_all(
    const float* __restrict__ W1, const float* __restrict__ W2,
    const float* __restrict__ Wo, const float* __restrict__ eg,
    const float* __restrict__ eb, __hip_bfloat16* __restrict__ W1T,
    __hip_bfloat16* __restrict__ W2T, __hip_bfloat16* __restrict__ WoT,
    float* __restrict__ b1a, float* __restrict__ b2a)
{
    __shared__ float tile[64][66];
    __shared__ float sg[64], sb[64];
    const int z   = blockIdx.z;
    const int mat = z >> 3;          // 0:W1 1:W2 2:Wo
    const int e   = z & 7;
    const int R   = (mat == 2) ? HH : DD;
    const int C   = (mat == 2) ? DD : HH;
    const int cT  = C >> 6;
    const int bx  = blockIdx.x;      // 0..1023
    const int c0  = (bx % cT) * 64;
    const int r0  = (bx / cT) * 64;
    const float* src = (mat == 0) ? W1 : (mat == 1) ? W2 : Wo;
    __hip_bfloat16* dst = (mat == 0) ? W1T : (mat == 1) ? W2T : WoT;
    const bool SC = (mat < 2);
    float* badd = (mat == 0) ? b1a : b2a;
    const int t = threadIdx.x;

    const float* s = src + (size_t)e * R * C + (size_t)r0 * C + c0;
    if (SC && t < 64) {
        sg[t] = eg[e * DD + r0 + t];
        sb[t] = eb[e * DD + r0 + t];
    }
    #pragma unroll
    for (int i = 0; i < 4; i++) {
        const int rr = i * 16 + (t >> 4);
        const int cc = (t & 15) * 4;
        const float4 v = *(const float4*)(s + (size_t)rr * C + cc);
        tile[rr][cc] = v.x; tile[rr][cc + 1] = v.y;
        tile[rr][cc + 2] = v.z; tile[rr][cc + 3] = v.w;
    }
    __syncthreads();

    __hip_bfloat16* d = dst + (size_t)e * R * C + (size_t)c0 * R + r0;
    #pragma unroll
    for (int i = 0; i < 2; i++) {
        const int id = t + 256 * i;
        const int cc = id >> 3;
        const int rb = (id & 7) * 8;
        union { u16x8 v; __hip_bfloat16 h[8]; } u;
        #pragma unroll
        for (int j = 0; j < 8; j++) {
            float v = tile[rb + j][cc];
            if (SC) v *= sg[rb + j];
            u.h[j] = __float2bfloat16(v);
        }
        *(u16x8*)(d + (size_t)cc * R + rb) = u.v;
    }
    if (SC && t < 64) {
        float sum = 0.f;
        #pragma unroll
        for (int rr = 0; rr < 64; rr++) sum += sb[rr] * tile[rr][t];
        atomicAdd(&badd[e * C + c0 + t], sum);
    }
}

// ---------------------------------------------------------------------------
// Per-token: LN1 -> router -> top2+softmax -> scatter; store LN2-normalized
// token as bf16 (eg/eb folded into weights); record slots per token.
// ---------------------------------------------------------------------------
__global__ __launch_bounds__(256) void token_kernel(
    const float* __restrict__ x, const float* __restrict__ lng, const float* __restrict__ lnb,
    const float* __restrict__ rw, __hip_bfloat16* __restrict__ xhat,
    int* __restrict__ counts, int* __restrict__ lists, float* __restrict__ gates,
    int* __restrict__ pairIdx)
{
    const int i = blockIdx.x;
    const int t = threadIdx.x;
    __shared__ float sA[256], sB[256];
    __shared__ float slog[32];

    float4 xv = ((const float4*)(x + (size_t)i * DD))[t];
    float s1 = xv.x + xv.y + xv.z + xv.w;
    float s2 = xv.x * xv.x + xv.y * xv.y + xv.z * xv.z + xv.w * xv.w;
    sA[t] = s1; sB[t] = s2;
    __syncthreads();
    for (int s = 128; s > 0; s >>= 1) {
        if (t < s) { sA[t] += sA[t + s]; sB[t] += sB[t + s]; }
        __syncthreads();
    }
    const float mu  = sA[0] * (1.0f / DD);
    const float var = sB[0] * (1.0f / DD) - mu * mu;
    const float rstd = rsqrtf(var + 1e-5f);
    __syncthreads();

    float4 gv = ((const float4*)lng)[t];
    float4 bv = ((const float4*)lnb)[t];
    float xf[4];
    xf[0] = (xv.x - mu) * rstd * gv.x + bv.x;
    xf[1] = (xv.y - mu) * rstd * gv.y + bv.y;
    xf[2] = (xv.z - mu) * rstd * gv.z + bv.z;
    xf[3] = (xv.w - mu) * rstd * gv.w + bv.w;

    float lp[8];
    #pragma unroll
    for (int e = 0; e < 8; e++) lp[e] = 0.f;
    {
        const float4* r4 = (const float4*)(rw + (size_t)(t * 4) * EE);
        #pragma unroll
        for (int j = 0; j < 4; j++) {
            float4 ra = r4[j * 2], rb = r4[j * 2 + 1];
            lp[0] += xf[j] * ra.x; lp[1] += xf[j] * ra.y;
            lp[2] += xf[j] * ra.z; lp[3] += xf[j] * ra.w;
            lp[4] += xf[j] * rb.x; lp[5] += xf[j] * rb.y;
            lp[6] += xf[j] * rb.z; lp[7] += xf[j] * rb.w;
        }
    }
    const int lane = t & 63, wid = t >> 6;
    #pragma unroll
    for (int e = 0; e < 8; e++) {
        float v = lp[e];
        #pragma unroll
        for (int o = 32; o > 0; o >>= 1) v += __shfl_down(v, o, 64);
        if (lane == 0) slog[e * 4 + wid] = v;
    }

    s1 = xf[0] + xf[1] + xf[2] + xf[3];
    s2 = xf[0] * xf[0] + xf[1] * xf[1] + xf[2] * xf[2] + xf[3] * xf[3];
    sA[t] = s1; sB[t] = s2;
    __syncthreads();
    for (int s = 128; s > 0; s >>= 1) {
        if (t < s) { sA[t] += sA[t + s]; sB[t] += sB[t + s]; }
        __syncthreads();
    }
    const float mu2  = sA[0] * (1.0f / DD);
    const float var2 = sB[0] * (1.0f / DD) - mu2 * mu2;
    const float rstd2 = rsqrtf(var2 + 1e-5f);

    union { ushort4 v; __hip_bfloat16 h[4]; } u;
    u.h[0] = __float2bfloat16((xf[0] - mu2) * rstd2);
    u.h[1] = __float2bfloat16((xf[1] - mu2) * rstd2);
    u.h[2] = __float2bfloat16((xf[2] - mu2) * rstd2);
    u.h[3] = __float2bfloat16((xf[3] - mu2) * rstd2);
    ((ushort4*)(xhat + (size_t)i * DD))[t] = u.v;

    if (t == 0) {
        float lg[8];
        #pragma unroll
        for (int e = 0; e < 8; e++)
            lg[e] = slog[e * 4] + slog[e * 4 + 1] + slog[e * 4 + 2] + slog[e * 4 + 3];
        int i0 = 0;
        #pragma unroll
        for (int e = 1; e < 8; e++) if (lg[e] > lg[i0]) i0 = e;
        int i1 = (i0 == 0) ? 1 : 0;
        #pragma unroll
        for (int e = 0; e < 8; e++) { if (e != i0 && lg[e] > lg[i1]) i1 = e; }
        const float ex = __expf(lg[i1] - lg[i0]);
        const float g0 = 1.f / (1.f + ex);
        const float g1 = ex / (1.f + ex);
        int p0 = atomicAdd(&counts[i0], 1);
        lists[i0 * NN + p0] = i; gates[i0 * NN + p0] = g0;
        int p1 = atomicAdd(&counts[i1], 1);
        lists[i1 * NN + p1] = i; gates[i1 * NN + p1] = g1;
        pairIdx[2 * i]     = i0 * NN + p0;
        pairIdx[2 * i + 1] = i1 * NN + p1;
    }
}

// ---------------------------------------------------------------------------
// GEMM1 (R8-proven config): 16x16x32, 4 waves, BM=128, BK=32, 128 h-cols x
// {W1,W2}, 48KB LDS, fully unrolled K-loop, verified conflict-free swizzle.
// ---------------------------------------------------------------------------
__global__ __launch_bounds__(256, 2) void gemm1_kernel(
    const __hip_bfloat16* __restrict__ xhat,
    const __hip_bfloat16* __restrict__ w1t, const __hip_bfloat16* __restrict__ w2t,
    const float* __restrict__ b1, const float* __restrict__ b2,
    const float* __restrict__ b1a, const float* __restrict__ b2a,
    const int* __restrict__ counts, const int* __restrict__ lists,
    __hip_bfloat16* __restrict__ hid)
{
    const int gid  = blockIdx.x;            // 0..4095
    const int xcd  = gid & 7;
    const int rest = gid >> 3;              // 0..511
    const int m    = rest & 15;
    const int pidx = rest >> 4;             // 0..31
    const int panel = xcd + 8 * pidx;       // 0..255: all m-blocks of panel on one XCD
    const int e   = panel >> 5;
    const int h0  = (panel & 31) * 128;
    const int cnt = counts[e];
    const int m0  = m * 128;
    if (m0 >= cnt) return;
    int base = 0;
    #pragma unroll
    for (int j = 0; j < 8; j++) base += (j < e) ? counts[j] : 0;

    __shared__ __align__(16) __hip_bfloat16 As[2][128 * 32];   // 8KB x2
    __shared__ __align__(16) __hip_bfloat16 Bs[2][256 * 32];   // 16KB x2: rows 0-127 W1, 128-255 W2
    __shared__ int toks[128];

    const int t = threadIdx.x, lane = t & 63, w = t >> 6;   // w = wn 0..3
    const int rsel = lane & 15, crd = lane >> 4;
    const int lr = lane >> 2;                               // staging row-in-16
    const int cl = (lane & 3) ^ ((lane >> 3) & 3);          // inverse-swizzled src chunk
    const int koff = (crd ^ ((rsel >> 1) & 3)) * 8;         // frag-read chunk

    if (t < 128) toks[t] = lists[e * NN + min(m0 + t, cnt - 1)];

    f32x4 acc1[8][2], acc2[8][2];
    const f32x4 z4 = {0.f, 0.f, 0.f, 0.f};
    #pragma unroll
    for (int q = 0; q < 8; q++) {
        acc1[q][0] = z4; acc1[q][1] = z4;
        acc2[q][0] = z4; acc2[q][1] = z4;
    }

    __syncthreads();                        // toks visible

    const __hip_bfloat16* pA[2];
    #pragma unroll
    for (int i = 0; i < 2; i++)
        pA[i] = xhat + (size_t)toks[w * 32 + i * 16 + lr] * DD + cl * 8;
    const __hip_bfloat16* pB[4];
    {
        const __hip_bfloat16* wsel = (w < 2) ? w1t : w2t;
        #pragma unroll
        for (int i = 0; i < 4; i++) {
            const int brow = (w & 1) * 64 + i * 16 + lr;    // row within matrix
            pB[i] = wsel + ((size_t)e * HH + h0 + brow) * DD + cl * 8;
        }
    }

    auto STAGE = [&](int buf, int ko) {
        #pragma unroll
        for (int i = 0; i < 2; i++)
            __builtin_amdgcn_global_load_lds(AS1P(pA[i] + ko), AS3P(&As[buf][w * 1024 + i * 512]), 16, 0, 0);
        #pragma unroll
        for (int i = 0; i < 4; i++)
            __builtin_amdgcn_global_load_lds(AS1P(pB[i] + ko), AS3P(&Bs[buf][w * 2048 + i * 512]), 16, 0, 0);
    };
    auto COMPUTE = [&](int buf) {
        bf16x8 af[8], b1q[2], b2q[2];
        #pragma unroll
        for (int mi = 0; mi < 8; mi++)
            af[mi] = *(const bf16x8*)&As[buf][(mi * 16 + rsel) * 32 + koff];
        #pragma unroll
        for (int ni = 0; ni < 2; ni++) {
            b1q[ni] = *(const bf16x8*)&Bs[buf][(w * 32 + ni * 16 + rsel) * 32 + koff];
            b2q[ni] = *(const bf16x8*)&Bs[buf][(4096 + (w * 32 + ni * 16 + rsel) * 32) + koff];
        }
        __builtin_amdgcn_s_setprio(1);
        #pragma unroll
        for (int mi = 0; mi < 8; mi++)
            #pragma unroll
            for (int ni = 0; ni < 2; ni++) {
                acc1[mi][ni] = mfma16(af[mi], b1q[ni], acc1[mi][ni]);
                acc2[mi][ni] = mfma16(af[mi], b2q[ni], acc2[mi][ni]);
            }
        __builtin_amdgcn_s_setprio(0);
    };

    STAGE(0, 0);
    __syncthreads();
    #pragma unroll
    for (int it = 0; it < 15; ++it) {
        STAGE(1, it * 64 + 32); COMPUTE(0); __syncthreads();
        STAGE(0, it * 64 + 64); COMPUTE(1); __syncthreads();
    }
    STAGE(1, 992); COMPUTE(0); __syncthreads();
    COMPUTE(1);

    const int rq = (lane >> 4) * 4, cq = lane & 15;
    #pragma unroll
    for (int ni = 0; ni < 2; ni++) {
        const int hcol = h0 + w * 32 + ni * 16 + cq;
        const float bb1 = b1[e * HH + hcol] + b1a[e * HH + hcol];
        const float bb2 = b2[e * HH + hcol] + b2a[e * HH + hcol];
        #pragma unroll
        for (int mi = 0; mi < 8; mi++) {
            f32x4 v1 = acc1[mi][ni];
            f32x4 v2 = acc2[mi][ni];
            #pragma unroll
            for (int r = 0; r < 4; r++) {
                const int pos = m0 + mi * 16 + rq + r;
                if (pos < cnt) {
                    float x1 = v1[r] + bb1;
                    float x2 = v2[r] + bb2;
                    x2 = fminf(fmaxf(x2, -20.f), 20.f);
                    float hv = x1 * (x2 / (1.f + __expf(-x2)));
                    hv = fminf(fmaxf(hv, -1e4f), 1e4f);
                    hid[(size_t)(base + pos) * HH + hcol] = __float2bfloat16(hv);
                }
            }
        }
    }
}

// ---------------------------------------------------------------------------
// GEMM2 v11: FULL-K (no split), BM=128, BN=128, BK=32, 4 waves (pure-N split),
// 33KB LDS. Epilogue computes EXACT per-expert clip(acc+bo) then atomicAdds
// gate*v into zeroed out (2 fp32 contributions/element -> deterministic).
// Deletes P partials (256MB traffic) + combine kernel.
// ---------------------------------------------------------------------------
__global__ __launch_bounds__(256, 2) void gemm2_kernel(
    const __hip_bfloat16* __restrict__ hid, const __hip_bfloat16* __restrict__ wot,
    const float* __restrict__ bo, const int* __restrict__ counts,
    const int* __restrict__ lists, const float* __restrict__ gates,
    float* __restrict__ out)
{
    const int gid  = blockIdx.x;            // 0..1023
    const int xcd  = gid & 7;
    const int rest = gid >> 3;              // 0..127
    const int m    = rest & 15;
    const int pidx = rest >> 4;             // 0..7
    const int panel = xcd + 8 * pidx;       // 0..63: all m-blocks of panel on one XCD
    const int e   = panel >> 3;
    const int d0  = (panel & 7) * 128;
    const int cnt = counts[e];
    const int m0  = m * 128;
    if (m0 >= cnt) return;
    int base = 0;
    #pragma unroll
    for (int j = 0; j < 8; j++) base += (j < e) ? counts[j] : 0;

    __shared__ __align__(16) __hip_bfloat16 As[2][128 * 32];   // 8KB x2
    __shared__ __align__(16) __hip_bfloat16 Bs[2][128 * 32];   // 8KB x2
    __shared__ int  toks[128];
    __shared__ float gts[128];

    const int t = threadIdx.x, lane = t & 63, w = t >> 6;
    const int rsel = lane & 15, crd = lane >> 4;
    const int lr = lane >> 2;
    const int cl = (lane & 3) ^ ((lane >> 3) & 3);
    const int koff = (crd ^ ((rsel >> 1) & 3)) * 8;

    if (t < 128) {
        const int idx = e * NN + min(m0 + t, cnt - 1);
        toks[t] = lists[idx];
        gts[t]  = gates[idx];
    }

    f32x4 acc[8][2];
    const f32x4 z4 = {0.f, 0.f, 0.f, 0.f};
    #pragma unroll
    for (int q = 0; q < 8; q++) { acc[q][0] = z4; acc[q][1] = z4; }

    __syncthreads();

    const __hip_bfloat16* pA[2];
    #pragma unroll
    for (int i = 0; i < 2; i++)
        pA[i] = hid + (size_t)(base + min(m0 + w * 32 + i * 16 + lr, cnt - 1)) * HH + cl * 8;
    const __hip_bfloat16* pB[2];
    #pragma unroll
    for (int i = 0; i < 2; i++)
        pB[i] = wot + ((size_t)e * DD + d0 + w * 32 + i * 16 + lr) * HH + cl * 8;

    auto STAGE = [&](int buf, int ko) {
        #pragma unroll
        for (int i = 0; i < 2; i++)
            __builtin_amdgcn_global_load_lds(AS1P(pA[i] + ko), AS3P(&As[buf][w * 1024 + i * 512]), 16, 0, 0);
        #pragma unroll
        for (int i = 0; i < 2; i++)
            __builtin_amdgcn_global_load_lds(AS1P(pB[i] + ko), AS3P(&Bs[buf][w * 1024 + i * 512]), 16, 0, 0);
    };
    auto COMPUTE = [&](int buf) {
        bf16x8 af[8], bq[2];
        #pragma unroll
        for (int mi = 0; mi < 8; mi++)
            af[mi] = *(const bf16x8*)&As[buf][(mi * 16 + rsel) * 32 + koff];
        #pragma unroll
        for (int ni = 0; ni < 2; ni++)
            bq[ni] = *(const bf16x8*)&Bs[buf][(w * 32 + ni * 16 + rsel) * 32 + koff];
        __builtin_amdgcn_s_setprio(1);
        #pragma unroll
        for (int mi = 0; mi < 8; mi++)
            #pragma unroll
            for (int ni = 0; ni < 2; ni++)
                acc[mi][ni] = mfma16(af[mi], bq[ni], acc[mi][ni]);
        __builtin_amdgcn_s_setprio(0);
    };

    STAGE(0, 0);
    __syncthreads();
    int ko = 0;
    #pragma unroll 1
    for (int it = 0; it < 63; ++it) {
        STAGE(1, ko + 32); COMPUTE(0); __syncthreads();
        STAGE(0, ko + 64); COMPUTE(1); __syncthreads();
        ko += 64;
    }
    STAGE(1, 4064); COMPUTE(0); __syncthreads();
    COMPUTE(1);

    const int rq = (lane >> 4) * 4, cq = lane & 15;
    #pragma unroll
    for (int ni = 0; ni < 2; ni++) {
        const int dcol = d0 + w * 32 + ni * 16 + cq;
        const float bov = bo[e * DD + dcol];
        #pragma unroll
        for (int mi = 0; mi < 8; mi++) {
            f32x4 v4 = acc[mi][ni];
            #pragma unroll
            for (int r = 0; r < 4; r++) {
                const int lpos = mi * 16 + rq + r;
                const int pos  = m0 + lpos;
                if (pos < cnt) {
                    float v = v4[r] + bov;
                    v = fminf(fmaxf(v, -1e4f), 1e4f);
                    atomicAdd(out + (size_t)toks[lpos] * DD + dcol, gts[lpos] * v);
                }
            }
        }
    }
}

// ---------------------------------------------------------------------------
extern "C" void kernel_launch(void* const* d_in, const int* in_sizes, int n_in,
                              void* d_out, int out_size, void* d_ws, size_t ws_size,
                              hipStream_t stream)
{
    const float* x   = (const float*)d_in[0];
    const float* lng = (const float*)d_in[1];
    const float* lnb = (const float*)d_in[2];
    const float* rw  = (const float*)d_in[3];
    const float* eg  = (const float*)d_in[4];
    const float* eb  = (const float*)d_in[5];
    const float* W1  = (const float*)d_in[6];
    const float* b1  = (const float*)d_in[7];
    const float* W2  = (const float*)d_in[8];
    const float* b2  = (const float*)d_in[9];
    const float* Wo  = (const float*)d_in[10];
    const float* bo  = (const float*)d_in[11];
    float* out = (float*)d_out;

    char* ws = (char*)d_ws;
    const size_t WSZ = (size_t)EE * HH * DD * 2;      // 64MB per weight matrix
    __hip_bfloat16* W1T  = (__hip_bfloat16*)(ws);
    __hip_bfloat16* W2T  = (__hip_bfloat16*)(ws + WSZ);
    __hip_bfloat16* WoT  = (__hip_bfloat16*)(ws + 2 * WSZ);
    __hip_bfloat16* xhat = (__hip_bfloat16*)(ws + 3 * WSZ);
    __hip_bfloat16* hid  = (__hip_bfloat16*)(ws + 3 * WSZ + (size_t)NN * DD * 2);
    char* small = ws + 3 * WSZ + (size_t)NN * DD * 2 + (size_t)2 * NN * HH * 2;
    int*   counts  = (int*)small;
    float* b1a     = (float*)(small + 256);
    float* b2a     = (float*)(small + 256 + 131072);
    int*   lists   = (int*)(small + 256 + 2 * 131072);
    float* gates   = (float*)(small + 256 + 3 * 131072);
    int*   pairIdx = (int*)(small + 256 + 4 * 131072);

    hipMemsetAsync(d_out, 0, (size_t)out_size * sizeof(float), stream);
    hipMemsetAsync(small, 0, 256 + 2 * 131072, stream);   // counts + b1a + b2a

    transpose_all<<<dim3(1024, 1, 24), 256, 0, stream>>>(
        W1, W2, Wo, eg, eb, W1T, W2T, WoT, b1a, b2a);

    token_kernel<<<NN, 256, 0, stream>>>(x, lng, lnb, rw, xhat, counts, lists, gates, pairIdx);

    gemm1_kernel<<<4096, 256, 0, stream>>>(
        xhat, W1T, W2T, b1, b2, b1a, b2a, counts, lists, hid);
    gemm2_kernel<<<1024, 256, 0, stream>>>(
        hid, WoT, bo, counts, lists, gates, out);
}

// Round 12
// 541.569 us; speedup vs baseline: 1.0470x; 1.0236x over previous
//
#include <hip/hip_runtime.h>
#include <hip/hip_bf16.h>

#define DD 1024
#define HH 4096
#define EE 8
#define NN 4096   // B*T tokens

typedef __attribute__((ext_vector_type(8))) short bf16x8;
typedef __attribute__((ext_vector_type(4))) float f32x4;
typedef __attribute__((ext_vector_type(8))) unsigned short u16x8;

#define AS1P(p) ((__attribute__((address_space(1))) void*)(unsigned long long)(const void*)(p))
#define AS3P(p) ((__attribute__((address_space(3))) void*)(unsigned int)(unsigned long long)(const void*)(p))

__device__ inline f32x4 mfma16(bf16x8 a, bf16x8 b, f32x4 c) {
    return __builtin_amdgcn_mfma_f32_16x16x32_bf16(a, b, c, 0, 0, 0);
}

// ---------------------------------------------------------------------------
// Fused transpose + fp32->bf16, v2: 128(r) x 64(c) tiles -> 256B write
// segments (was 128B). z = 0..7: W1, 8..15: W2, 16..23: Wo. grid.x = 512 all.
// ---------------------------------------------------------------------------
__global__ __launch_bounds__(256) void transpose_all(
    const float* __restrict__ W1, const float* __restrict__ W2,
    const float* __restrict__ Wo, const float* __restrict__ eg,
    const float* __restrict__ eb, __hip_bfloat16* __restrict__ W1T,
    __hip_bfloat16* __restrict__ W2T, __hip_bfloat16* __restrict__ WoT,
    float* __restrict__ b1a, float* __restrict__ b2a)
{
    __shared__ float tile[128][65];
    __shared__ float sg[128], sb[128];
    const int z   = blockIdx.z;
    const int mat = z >> 3;          // 0:W1 1:W2 2:Wo
    const int e   = z & 7;
    const int R   = (mat == 2) ? HH : DD;
    const int C   = (mat == 2) ? DD : HH;
    const int cT  = C >> 6;
    const int bx  = blockIdx.x;      // 0..511
    const int c0  = (bx % cT) * 64;
    const int r0  = (bx / cT) * 128;
    const float* src = (mat == 0) ? W1 : (mat == 1) ? W2 : Wo;
    __hip_bfloat16* dst = (mat == 0) ? W1T : (mat == 1) ? W2T : WoT;
    const bool SC = (mat < 2);
    float* badd = (mat == 0) ? b1a : b2a;
    const int t = threadIdx.x;

    const float* s = src + (size_t)e * R * C + (size_t)r0 * C + c0;
    if (SC && t < 128) {
        sg[t] = eg[e * DD + r0 + t];
        sb[t] = eb[e * DD + r0 + t];
    }
    #pragma unroll
    for (int i = 0; i < 8; i++) {
        const int rr = i * 16 + (t >> 4);
        const int cc = (t & 15) * 4;
        const float4 v = *(const float4*)(s + (size_t)rr * C + cc);
        tile[rr][cc] = v.x; tile[rr][cc + 1] = v.y;
        tile[rr][cc + 2] = v.z; tile[rr][cc + 3] = v.w;
    }
    __syncthreads();

    __hip_bfloat16* d = dst + (size_t)e * R * C + (size_t)c0 * R + r0;
    #pragma unroll
    for (int i = 0; i < 4; i++) {
        const int id = t + 256 * i;      // 0..1023
        const int cc = id >> 4;          // dst row (src col) 0..63
        const int rb = (id & 15) * 8;    // dst col (src row) block 0..120
        union { u16x8 v; __hip_bfloat16 h[8]; } u;
        #pragma unroll
        for (int j = 0; j < 8; j++) {
            float v = tile[rb + j][cc];
            if (SC) v *= sg[rb + j];
            u.h[j] = __float2bfloat16(v);
        }
        *(u16x8*)(d + (size_t)cc * R + rb) = u.v;
    }
    if (SC && t < 64) {
        float sum = 0.f;
        #pragma unroll
        for (int rr = 0; rr < 128; rr++) sum += sb[rr] * tile[rr][t];
        atomicAdd(&badd[e * C + c0 + t], sum);
    }
}

// ---------------------------------------------------------------------------
// Per-token: LN1 -> router -> top2+softmax -> scatter; store LN2-normalized
// token as bf16 (eg/eb folded into weights); record slots per token.
// ---------------------------------------------------------------------------
__global__ __launch_bounds__(256) void token_kernel(
    const float* __restrict__ x, const float* __restrict__ lng, const float* __restrict__ lnb,
    const float* __restrict__ rw, __hip_bfloat16* __restrict__ xhat,
    int* __restrict__ counts, int* __restrict__ lists, float* __restrict__ gates,
    int* __restrict__ pairIdx)
{
    const int i = blockIdx.x;
    const int t = threadIdx.x;
    __shared__ float sA[256], sB[256];
    __shared__ float slog[32];

    float4 xv = ((const float4*)(x + (size_t)i * DD))[t];
    float s1 = xv.x + xv.y + xv.z + xv.w;
    float s2 = xv.x * xv.x + xv.y * xv.y + xv.z * xv.z + xv.w * xv.w;
    sA[t] = s1; sB[t] = s2;
    __syncthreads();
    for (int s = 128; s > 0; s >>= 1) {
        if (t < s) { sA[t] += sA[t + s]; sB[t] += sB[t + s]; }
        __syncthreads();
    }
    const float mu  = sA[0] * (1.0f / DD);
    const float var = sB[0] * (1.0f / DD) - mu * mu;
    const float rstd = rsqrtf(var + 1e-5f);
    __syncthreads();

    float4 gv = ((const float4*)lng)[t];
    float4 bv = ((const float4*)lnb)[t];
    float xf[4];
    xf[0] = (xv.x - mu) * rstd * gv.x + bv.x;
    xf[1] = (xv.y - mu) * rstd * gv.y + bv.y;
    xf[2] = (xv.z - mu) * rstd * gv.z + bv.z;
    xf[3] = (xv.w - mu) * rstd * gv.w + bv.w;

    float lp[8];
    #pragma unroll
    for (int e = 0; e < 8; e++) lp[e] = 0.f;
    {
        const float4* r4 = (const float4*)(rw + (size_t)(t * 4) * EE);
        #pragma unroll
        for (int j = 0; j < 4; j++) {
            float4 ra = r4[j * 2], rb = r4[j * 2 + 1];
            lp[0] += xf[j] * ra.x; lp[1] += xf[j] * ra.y;
            lp[2] += xf[j] * ra.z; lp[3] += xf[j] * ra.w;
            lp[4] += xf[j] * rb.x; lp[5] += xf[j] * rb.y;
            lp[6] += xf[j] * rb.z; lp[7] += xf[j] * rb.w;
        }
    }
    const int lane = t & 63, wid = t >> 6;
    #pragma unroll
    for (int e = 0; e < 8; e++) {
        float v = lp[e];
        #pragma unroll
        for (int o = 32; o > 0; o >>= 1) v += __shfl_down(v, o, 64);
        if (lane == 0) slog[e * 4 + wid] = v;
    }

    s1 = xf[0] + xf[1] + xf[2] + xf[3];
    s2 = xf[0] * xf[0] + xf[1] * xf[1] + xf[2] * xf[2] + xf[3] * xf[3];
    sA[t] = s1; sB[t] = s2;
    __syncthreads();
    for (int s = 128; s > 0; s >>= 1) {
        if (t < s) { sA[t] += sA[t + s]; sB[t] += sB[t + s]; }
        __syncthreads();
    }
    const float mu2  = sA[0] * (1.0f / DD);
    const float var2 = sB[0] * (1.0f / DD) - mu2 * mu2;
    const float rstd2 = rsqrtf(var2 + 1e-5f);

    union { ushort4 v; __hip_bfloat16 h[4]; } u;
    u.h[0] = __float2bfloat16((xf[0] - mu2) * rstd2);
    u.h[1] = __float2bfloat16((xf[1] - mu2) * rstd2);
    u.h[2] = __float2bfloat16((xf[2] - mu2) * rstd2);
    u.h[3] = __float2bfloat16((xf[3] - mu2) * rstd2);
    ((ushort4*)(xhat + (size_t)i * DD))[t] = u.v;

    if (t == 0) {
        float lg[8];
        #pragma unroll
        for (int e = 0; e < 8; e++)
            lg[e] = slog[e * 4] + slog[e * 4 + 1] + slog[e * 4 + 2] + slog[e * 4 + 3];
        int i0 = 0;
        #pragma unroll
        for (int e = 1; e < 8; e++) if (lg[e] > lg[i0]) i0 = e;
        int i1 = (i0 == 0) ? 1 : 0;
        #pragma unroll
        for (int e = 0; e < 8; e++) { if (e != i0 && lg[e] > lg[i1]) i1 = e; }
        const float ex = __expf(lg[i1] - lg[i0]);
        const float g0 = 1.f / (1.f + ex);
        const float g1 = ex / (1.f + ex);
        int p0 = atomicAdd(&counts[i0], 1);
        lists[i0 * NN + p0] = i; gates[i0 * NN + p0] = g0;
        int p1 = atomicAdd(&counts[i1], 1);
        lists[i1 * NN + p1] = i; gates[i1 * NN + p1] = g1;
        pairIdx[2 * i]     = i0 * NN + p0;
        pairIdx[2 * i + 1] = i1 * NN + p1;
    }
}

// ---------------------------------------------------------------------------
// GEMM1 (R8-proven config, unchanged): 16x16x32, 4 waves, BM=128, BK=32,
// 128 h-cols x {W1,W2}, 48KB LDS, unrolled K-loop, conflict-free swizzle.
// ---------------------------------------------------------------------------
__global__ __launch_bounds__(256, 2) void gemm1_kernel(
    const __hip_bfloat16* __restrict__ xhat,
    const __hip_bfloat16* __restrict__ w1t, const __hip_bfloat16* __restrict__ w2t,
    const float* __restrict__ b1, const float* __restrict__ b2,
    const float* __restrict__ b1a, const float* __restrict__ b2a,
    const int* __restrict__ counts, const int* __restrict__ lists,
    __hip_bfloat16* __restrict__ hid)
{
    const int gid  = blockIdx.x;            // 0..4095
    const int xcd  = gid & 7;
    const int rest = gid >> 3;              // 0..511
    const int m    = rest & 15;
    const int pidx = rest >> 4;             // 0..31
    const int panel = xcd + 8 * pidx;       // 0..255
    const int e   = panel >> 5;
    const int h0  = (panel & 31) * 128;
    const int cnt = counts[e];
    const int m0  = m * 128;
    if (m0 >= cnt) return;
    int base = 0;
    #pragma unroll
    for (int j = 0; j < 8; j++) base += (j < e) ? counts[j] : 0;

    __shared__ __align__(16) __hip_bfloat16 As[2][128 * 32];
    __shared__ __align__(16) __hip_bfloat16 Bs[2][256 * 32];
    __shared__ int toks[128];

    const int t = threadIdx.x, lane = t & 63, w = t >> 6;
    const int rsel = lane & 15, crd = lane >> 4;
    const int lr = lane >> 2;
    const int cl = (lane & 3) ^ ((lane >> 3) & 3);
    const int koff = (crd ^ ((rsel >> 1) & 3)) * 8;

    if (t < 128) toks[t] = lists[e * NN + min(m0 + t, cnt - 1)];

    f32x4 acc1[8][2], acc2[8][2];
    const f32x4 z4 = {0.f, 0.f, 0.f, 0.f};
    #pragma unroll
    for (int q = 0; q < 8; q++) {
        acc1[q][0] = z4; acc1[q][1] = z4;
        acc2[q][0] = z4; acc2[q][1] = z4;
    }

    __syncthreads();

    const __hip_bfloat16* pA[2];
    #pragma unroll
    for (int i = 0; i < 2; i++)
        pA[i] = xhat + (size_t)toks[w * 32 + i * 16 + lr] * DD + cl * 8;
    const __hip_bfloat16* pB[4];
    {
        const __hip_bfloat16* wsel = (w < 2) ? w1t : w2t;
        #pragma unroll
        for (int i = 0; i < 4; i++) {
            const int brow = (w & 1) * 64 + i * 16 + lr;
            pB[i] = wsel + ((size_t)e * HH + h0 + brow) * DD + cl * 8;
        }
    }

    auto STAGE = [&](int buf, int ko) {
        #pragma unroll
        for (int i = 0; i < 2; i++)
            __builtin_amdgcn_global_load_lds(AS1P(pA[i] + ko), AS3P(&As[buf][w * 1024 + i * 512]), 16, 0, 0);
        #pragma unroll
        for (int i = 0; i < 4; i++)
            __builtin_amdgcn_global_load_lds(AS1P(pB[i] + ko), AS3P(&Bs[buf][w * 2048 + i * 512]), 16, 0, 0);
    };
    auto COMPUTE = [&](int buf) {
        bf16x8 af[8], b1q[2], b2q[2];
        #pragma unroll
        for (int mi = 0; mi < 8; mi++)
            af[mi] = *(const bf16x8*)&As[buf][(mi * 16 + rsel) * 32 + koff];
        #pragma unroll
        for (int ni = 0; ni < 2; ni++) {
            b1q[ni] = *(const bf16x8*)&Bs[buf][(w * 32 + ni * 16 + rsel) * 32 + koff];
            b2q[ni] = *(const bf16x8*)&Bs[buf][(4096 + (w * 32 + ni * 16 + rsel) * 32) + koff];
        }
        __builtin_amdgcn_s_setprio(1);
        #pragma unroll
        for (int mi = 0; mi < 8; mi++)
            #pragma unroll
            for (int ni = 0; ni < 2; ni++) {
                acc1[mi][ni] = mfma16(af[mi], b1q[ni], acc1[mi][ni]);
                acc2[mi][ni] = mfma16(af[mi], b2q[ni], acc2[mi][ni]);
            }
        __builtin_amdgcn_s_setprio(0);
    };

    STAGE(0, 0);
    __syncthreads();
    #pragma unroll
    for (int it = 0; it < 15; ++it) {
        STAGE(1, it * 64 + 32); COMPUTE(0); __syncthreads();
        STAGE(0, it * 64 + 64); COMPUTE(1); __syncthreads();
    }
    STAGE(1, 992); COMPUTE(0); __syncthreads();
    COMPUTE(1);

    const int rq = (lane >> 4) * 4, cq = lane & 15;
    #pragma unroll
    for (int ni = 0; ni < 2; ni++) {
        const int hcol = h0 + w * 32 + ni * 16 + cq;
        const float bb1 = b1[e * HH + hcol] + b1a[e * HH + hcol];
        const float bb2 = b2[e * HH + hcol] + b2a[e * HH + hcol];
        #pragma unroll
        for (int mi = 0; mi < 8; mi++) {
            f32x4 v1 = acc1[mi][ni];
            f32x4 v2 = acc2[mi][ni];
            #pragma unroll
            for (int r = 0; r < 4; r++) {
                const int pos = m0 + mi * 16 + rq + r;
                if (pos < cnt) {
                    float x1 = v1[r] + bb1;
                    float x2 = v2[r] + bb2;
                    x2 = fminf(fmaxf(x2, -20.f), 20.f);
                    float hv = x1 * (x2 / (1.f + __expf(-x2)));
                    hv = fminf(fmaxf(hv, -1e4f), 1e4f);
                    hid[(size_t)(base + pos) * HH + hcol] = __float2bfloat16(hv);
                }
            }
        }
    }
}

// ---------------------------------------------------------------------------
// GEMM2 v12: split-K=2, BM=128, BN=256, BK=32, 4 waves (pure-N), 48KB LDS.
// EXPERT = XCD mapping (e = gid&7): all m/sp/d-panel blocks of one expert
// co-locate on one XCD -> hid (the reuse-heavy A operand) stays L2-local.
// Raw partials to P0/P1; bias/clip/gate in combine.
// ---------------------------------------------------------------------------
__global__ __launch_bounds__(256, 2) void gemm2_kernel(
    const __hip_bfloat16* __restrict__ hid, const __hip_bfloat16* __restrict__ wot,
    const int* __restrict__ counts, float* __restrict__ P0, float* __restrict__ P1)
{
    const int gid = blockIdx.x;             // 0..1023
    const int e   = gid & 7;                // expert == XCD
    const int k_  = gid >> 3;               // 0..127
    const int m   = k_ & 15;
    const int sp  = (k_ >> 4) & 1;
    const int dp  = k_ >> 5;                // 0..3
    const int d0  = dp * 256;
    const int cnt = counts[e];
    const int m0  = m * 128;
    if (m0 >= cnt) return;
    int base = 0;
    #pragma unroll
    for (int j = 0; j < 8; j++) base += (j < e) ? counts[j] : 0;

    __shared__ __align__(16) __hip_bfloat16 As[2][128 * 32];   // 8KB x2
    __shared__ __align__(16) __hip_bfloat16 Bs[2][256 * 32];   // 16KB x2

    const int t = threadIdx.x, lane = t & 63, w = t >> 6;
    const int rsel = lane & 15, crd = lane >> 4;
    const int lr = lane >> 2;
    const int cl = (lane & 3) ^ ((lane >> 3) & 3);
    const int koff = (crd ^ ((rsel >> 1) & 3)) * 8;

    f32x4 acc[8][4];
    const f32x4 z4 = {0.f, 0.f, 0.f, 0.f};
    #pragma unroll
    for (int q = 0; q < 8; q++) {
        acc[q][0] = z4; acc[q][1] = z4; acc[q][2] = z4; acc[q][3] = z4;
    }

    const int kbase = sp * 2048;
    const __hip_bfloat16* pA[2];
    #pragma unroll
    for (int i = 0; i < 2; i++)
        pA[i] = hid + (size_t)(base + min(m0 + w * 32 + i * 16 + lr, cnt - 1)) * HH + kbase + cl * 8;
    const __hip_bfloat16* pB[4];
    #pragma unroll
    for (int i = 0; i < 4; i++)
        pB[i] = wot + ((size_t)e * DD + d0 + w * 64 + i * 16 + lr) * HH + kbase + cl * 8;

    auto STAGE = [&](int buf, int ko) {
        #pragma unroll
        for (int i = 0; i < 2; i++)
            __builtin_amdgcn_global_load_lds(AS1P(pA[i] + ko), AS3P(&As[buf][w * 1024 + i * 512]), 16, 0, 0);
        #pragma unroll
        for (int i = 0; i < 4; i++)
            __builtin_amdgcn_global_load_lds(AS1P(pB[i] + ko), AS3P(&Bs[buf][w * 2048 + i * 512]), 16, 0, 0);
    };
    auto COMPUTE = [&](int buf) {
        bf16x8 af[8], bq[4];
        #pragma unroll
        for (int mi = 0; mi < 8; mi++)
            af[mi] = *(const bf16x8*)&As[buf][(mi * 16 + rsel) * 32 + koff];
        #pragma unroll
        for (int ni = 0; ni < 4; ni++)
            bq[ni] = *(const bf16x8*)&Bs[buf][(w * 64 + ni * 16 + rsel) * 32 + koff];
        __builtin_amdgcn_s_setprio(1);
        #pragma unroll
        for (int mi = 0; mi < 8; mi++)
            #pragma unroll
            for (int ni = 0; ni < 4; ni++)
                acc[mi][ni] = mfma16(af[mi], bq[ni], acc[mi][ni]);
        __builtin_amdgcn_s_setprio(0);
    };

    STAGE(0, 0);
    __syncthreads();
    #pragma unroll
    for (int it = 0; it < 31; ++it) {
        STAGE(1, it * 64 + 32); COMPUTE(0); __syncthreads();
        STAGE(0, it * 64 + 64); COMPUTE(1); __syncthreads();
    }
    STAGE(1, 2016); COMPUTE(0); __syncthreads();
    COMPUTE(1);

    float* dst = sp ? P1 : P0;
    const int rq = (lane >> 4) * 4, cq = lane & 15;
    #pragma unroll
    for (int ni = 0; ni < 4; ni++) {
        const int dcol = d0 + w * 64 + ni * 16 + cq;
        #pragma unroll
        for (int mi = 0; mi < 8; mi++) {
            f32x4 v = acc[mi][ni];
            #pragma unroll
            for (int r = 0; r < 4; r++) {
                const int pos = m0 + mi * 16 + rq + r;
                if (pos < cnt)
                    dst[(size_t)(base + pos) * DD + dcol] = v[r];
            }
        }
    }
}

// ---------------------------------------------------------------------------
// Combine: out[token] = sum_slots gate * clip(P0[slot]+P1[slot]+bo[e], +-1e4)
// ---------------------------------------------------------------------------
__global__ __launch_bounds__(256) void combine_kernel(
    const float* __restrict__ P0, const float* __restrict__ P1,
    const float* __restrict__ bo, const int* __restrict__ counts,
    const int* __restrict__ pairIdx, const float* __restrict__ gates,
    float* __restrict__ out)
{
    const int i = blockIdx.x;
    const int t = threadIdx.x;
    const int s0 = pairIdx[2 * i], s1 = pairIdx[2 * i + 1];
    const int e0 = s0 >> 12, p0 = s0 & (NN - 1);
    const int e1 = s1 >> 12, p1 = s1 & (NN - 1);
    int b0 = 0, b1 = 0;
    #pragma unroll
    for (int j = 0; j < 8; j++) {
        const int c = counts[j];
        b0 += (j < e0) ? c : 0;
        b1 += (j < e1) ? c : 0;
    }
    const float g0 = gates[s0], g1 = gates[s1];
    const size_t r0 = (size_t)(b0 + p0) * DD, r1 = (size_t)(b1 + p1) * DD;
    const float4 a0 = ((const float4*)(P0 + r0))[t], c0 = ((const float4*)(P1 + r0))[t];
    const float4 a1 = ((const float4*)(P0 + r1))[t], c1 = ((const float4*)(P1 + r1))[t];
    const float4 q0 = ((const float4*)(bo + (size_t)e0 * DD))[t];
    const float4 q1 = ((const float4*)(bo + (size_t)e1 * DD))[t];
    float4 r;
    #pragma unroll
    for (int k = 0; k < 4; k++) {
        float v0 = ((const float*)&a0)[k] + ((const float*)&c0)[k] + ((const float*)&q0)[k];
        float v1 = ((const float*)&a1)[k] + ((const float*)&c1)[k] + ((const float*)&q1)[k];
        v0 = fminf(fmaxf(v0, -1e4f), 1e4f);
        v1 = fminf(fmaxf(v1, -1e4f), 1e4f);
        ((float*)&r)[k] = g0 * v0 + g1 * v1;
    }
    ((float4*)(out + (size_t)i * DD))[t] = r;
}

// ---------------------------------------------------------------------------
extern "C" void kernel_launch(void* const* d_in, const int* in_sizes, int n_in,
                              void* d_out, int out_size, void* d_ws, size_t ws_size,
                              hipStream_t stream)
{
    const float* x   = (const float*)d_in[0];
    const float* lng = (const float*)d_in[1];
    const float* lnb = (const float*)d_in[2];
    const float* rw  = (const float*)d_in[3];
    const float* eg  = (const float*)d_in[4];
    const float* eb  = (const float*)d_in[5];
    const float* W1  = (const float*)d_in[6];
    const float* b1  = (const float*)d_in[7];
    const float* W2  = (const float*)d_in[8];
    const float* b2  = (const float*)d_in[9];
    const float* Wo  = (const float*)d_in[10];
    const float* bo  = (const float*)d_in[11];
    float* out = (float*)d_out;

    char* ws = (char*)d_ws;
    const size_t WSZ = (size_t)EE * HH * DD * 2;      // 64MB per weight matrix
    __hip_bfloat16* W1T  = (__hip_bfloat16*)(ws);
    __hip_bfloat16* W2T  = (__hip_bfloat16*)(ws + WSZ);
    __hip_bfloat16* WoT  = (__hip_bfloat16*)(ws + 2 * WSZ);
    __hip_bfloat16* xhat = (__hip_bfloat16*)(ws + 3 * WSZ);
    __hip_bfloat16* hid  = (__hip_bfloat16*)(ws + 3 * WSZ + (size_t)NN * DD * 2);
    char* small = ws + 3 * WSZ + (size_t)NN * DD * 2 + (size_t)2 * NN * HH * 2;
    int*   counts  = (int*)small;
    float* b1a     = (float*)(small + 256);
    float* b2a     = (float*)(small + 256 + 131072);
    int*   lists   = (int*)(small + 256 + 2 * 131072);
    float* gates   = (float*)(small + 256 + 3 * 131072);
    int*   pairIdx = (int*)(small + 256 + 4 * 131072);
    // split-K partials (each 8192x1024 f32 = 32MB) alias W1T / W2T (dead after
    // gemm1; rewritten by transpose_all at the start of every call).
    float* P0 = (float*)(ws);
    float* P1 = (float*)(ws + WSZ);

    hipMemsetAsync(small, 0, 256 + 2 * 131072, stream);   // counts + b1a + b2a

    transpose_all<<<dim3(512, 1, 24), 256, 0, stream>>>(
        W1, W2, Wo, eg, eb, W1T, W2T, WoT, b1a, b2a);

    token_kernel<<<NN, 256, 0, stream>>>(x, lng, lnb, rw, xhat, counts, lists, gates, pairIdx);

    gemm1_kernel<<<4096, 256, 0, stream>>>(
        xhat, W1T, W2T, b1, b2, b1a, b2a, counts, lists, hid);
    gemm2_kernel<<<1024, 256, 0, stream>>>(
        hid, WoT, counts, P0, P1);
    combine_kernel<<<NN, 256, 0, stream>>>(P0, P1, bo, counts, pairIdx, gates, out);
}

// Round 13
// 494.745 us; speedup vs baseline: 1.1461x; 1.0946x over previous
//
#include <hip/hip_runtime.h>
#include <hip/hip_bf16.h>

#define DD 1024
#define HH 4096
#define EE 8
#define NN 4096   // B*T tokens

typedef __attribute__((ext_vector_type(8))) short bf16x8;
typedef __attribute__((ext_vector_type(4))) float f32x4;
typedef __attribute__((ext_vector_type(8))) unsigned short u16x8;

#define AS1P(p) ((__attribute__((address_space(1))) void*)(unsigned long long)(const void*)(p))
#define AS3P(p) ((__attribute__((address_space(3))) void*)(unsigned int)(unsigned long long)(const void*)(p))

__device__ inline f32x4 mfma16(bf16x8 a, bf16x8 b, f32x4 c) {
    return __builtin_amdgcn_mfma_f32_16x16x32_bf16(a, b, c, 0, 0, 0);
}

// ---------------------------------------------------------------------------
// prep_kernel: ONE dispatch fusing
//   blocks 0..8191   : transpose+convert W1 (0..4095) / W2 (4096..8191),
//                      eg-scaled, eb@W accumulated into b1a/b2a.
//                      128(r) x 64(c) tiles, 256B write segments.
//   blocks 8192..12287: per-token LN1 -> router -> top2 -> scatter + xhat.
// Independent work; fusion hides the token pass inside the transpose pass.
// ---------------------------------------------------------------------------
__global__ __launch_bounds__(256) void prep_kernel(
    const float* __restrict__ W1, const float* __restrict__ W2,
    const float* __restrict__ eg, const float* __restrict__ eb,
    __hip_bfloat16* __restrict__ W1T, __hip_bfloat16* __restrict__ W2T,
    float* __restrict__ b1a, float* __restrict__ b2a,
    const float* __restrict__ x, const float* __restrict__ lng,
    const float* __restrict__ lnb, const float* __restrict__ rw,
    __hip_bfloat16* __restrict__ xhat, int* __restrict__ counts,
    int* __restrict__ lists, float* __restrict__ gates, int* __restrict__ pairIdx)
{
    __shared__ __align__(16) char smem[34304];
    const int bid = blockIdx.x;
    const int t = threadIdx.x;

    if (bid < 8192) {
        // ---- W1/W2 transpose branch ----
        float (*tile)[65] = (float(*)[65])smem;          // 128 x 65 x 4B = 33280
        float* sg = (float*)(smem + 33280);              // 128 f
        float* sb = sg + 128;                            // 128 f
        const int mat   = bid >> 12;                     // 0:W1 1:W2
        const int rem   = bid & 4095;
        const int e     = rem >> 9;
        const int local = rem & 511;
        const int c0    = (local & 63) * 64;
        const int r0    = (local >> 6) * 128;
        const float* src = (mat ? W2 : W1) + (size_t)e * DD * HH + (size_t)r0 * HH + c0;
        __hip_bfloat16* dst = (mat ? W2T : W1T) + (size_t)e * HH * DD + (size_t)c0 * DD + r0;
        float* badd = mat ? b2a : b1a;

        if (t < 128) {
            sg[t] = eg[e * DD + r0 + t];
            sb[t] = eb[e * DD + r0 + t];
        }
        #pragma unroll
        for (int i = 0; i < 8; i++) {
            const int rr = i * 16 + (t >> 4);
            const int cc = (t & 15) * 4;
            const float4 v = *(const float4*)(src + (size_t)rr * HH + cc);
            tile[rr][cc] = v.x; tile[rr][cc + 1] = v.y;
            tile[rr][cc + 2] = v.z; tile[rr][cc + 3] = v.w;
        }
        __syncthreads();

        #pragma unroll
        for (int i = 0; i < 4; i++) {
            const int id = t + 256 * i;      // 0..1023
            const int cc = id >> 4;          // dst row (src col) 0..63
            const int rb = (id & 15) * 8;    // dst col (src row) block
            union { u16x8 v; __hip_bfloat16 h[8]; } u;
            #pragma unroll
            for (int j = 0; j < 8; j++)
                u.h[j] = __float2bfloat16(tile[rb + j][cc] * sg[rb + j]);
            *(u16x8*)(dst + (size_t)cc * DD + rb) = u.v;
        }
        if (t < 64) {
            float sum = 0.f;
            #pragma unroll
            for (int rr = 0; rr < 128; rr++) sum += sb[rr] * tile[rr][t];
            atomicAdd(&badd[e * HH + c0 + t], sum);
        }
        return;
    }

    // ---- token branch ----
    const int i = bid - 8192;
    float* sA = (float*)smem;
    float* sB = sA + 256;
    float* slog = sB + 256;

    float4 xv = ((const float4*)(x + (size_t)i * DD))[t];
    float s1 = xv.x + xv.y + xv.z + xv.w;
    float s2 = xv.x * xv.x + xv.y * xv.y + xv.z * xv.z + xv.w * xv.w;
    sA[t] = s1; sB[t] = s2;
    __syncthreads();
    for (int s = 128; s > 0; s >>= 1) {
        if (t < s) { sA[t] += sA[t + s]; sB[t] += sB[t + s]; }
        __syncthreads();
    }
    const float mu  = sA[0] * (1.0f / DD);
    const float var = sB[0] * (1.0f / DD) - mu * mu;
    const float rstd = rsqrtf(var + 1e-5f);
    __syncthreads();

    float4 gv = ((const float4*)lng)[t];
    float4 bv = ((const float4*)lnb)[t];
    float xf[4];
    xf[0] = (xv.x - mu) * rstd * gv.x + bv.x;
    xf[1] = (xv.y - mu) * rstd * gv.y + bv.y;
    xf[2] = (xv.z - mu) * rstd * gv.z + bv.z;
    xf[3] = (xv.w - mu) * rstd * gv.w + bv.w;

    float lp[8];
    #pragma unroll
    for (int e = 0; e < 8; e++) lp[e] = 0.f;
    {
        const float4* r4 = (const float4*)(rw + (size_t)(t * 4) * EE);
        #pragma unroll
        for (int j = 0; j < 4; j++) {
            float4 ra = r4[j * 2], rb = r4[j * 2 + 1];
            lp[0] += xf[j] * ra.x; lp[1] += xf[j] * ra.y;
            lp[2] += xf[j] * ra.z; lp[3] += xf[j] * ra.w;
            lp[4] += xf[j] * rb.x; lp[5] += xf[j] * rb.y;
            lp[6] += xf[j] * rb.z; lp[7] += xf[j] * rb.w;
        }
    }
    const int lane = t & 63, wid = t >> 6;
    #pragma unroll
    for (int e = 0; e < 8; e++) {
        float v = lp[e];
        #pragma unroll
        for (int o = 32; o > 0; o >>= 1) v += __shfl_down(v, o, 64);
        if (lane == 0) slog[e * 4 + wid] = v;
    }

    s1 = xf[0] + xf[1] + xf[2] + xf[3];
    s2 = xf[0] * xf[0] + xf[1] * xf[1] + xf[2] * xf[2] + xf[3] * xf[3];
    sA[t] = s1; sB[t] = s2;
    __syncthreads();
    for (int s = 128; s > 0; s >>= 1) {
        if (t < s) { sA[t] += sA[t + s]; sB[t] += sB[t + s]; }
        __syncthreads();
    }
    const float mu2  = sA[0] * (1.0f / DD);
    const float var2 = sB[0] * (1.0f / DD) - mu2 * mu2;
    const float rstd2 = rsqrtf(var2 + 1e-5f);

    union { ushort4 v; __hip_bfloat16 h[4]; } u;
    u.h[0] = __float2bfloat16((xf[0] - mu2) * rstd2);
    u.h[1] = __float2bfloat16((xf[1] - mu2) * rstd2);
    u.h[2] = __float2bfloat16((xf[2] - mu2) * rstd2);
    u.h[3] = __float2bfloat16((xf[3] - mu2) * rstd2);
    ((ushort4*)(xhat + (size_t)i * DD))[t] = u.v;

    if (t == 0) {
        float lg[8];
        #pragma unroll
        for (int e = 0; e < 8; e++)
            lg[e] = slog[e * 4] + slog[e * 4 + 1] + slog[e * 4 + 2] + slog[e * 4 + 3];
        int i0 = 0;
        #pragma unroll
        for (int e = 1; e < 8; e++) if (lg[e] > lg[i0]) i0 = e;
        int i1 = (i0 == 0) ? 1 : 0;
        #pragma unroll
        for (int e = 0; e < 8; e++) { if (e != i0 && lg[e] > lg[i1]) i1 = e; }
        const float ex = __expf(lg[i1] - lg[i0]);
        const float g0 = 1.f / (1.f + ex);
        const float g1 = ex / (1.f + ex);
        int p0 = atomicAdd(&counts[i0], 1);
        lists[i0 * NN + p0] = i; gates[i0 * NN + p0] = g0;
        int p1 = atomicAdd(&counts[i1], 1);
        lists[i1 * NN + p1] = i; gates[i1 * NN + p1] = g1;
        pairIdx[2 * i]     = i0 * NN + p0;
        pairIdx[2 * i + 1] = i1 * NN + p1;
    }
}

// ---------------------------------------------------------------------------
// GEMM1 (R8-proven config) FUSED with the Wo transpose:
//   blocks 0..4095   : gemm1 (16x16x32, 4 waves, BM=128, BK=32, 128 h-cols x
//                      {W1,W2}, 48KB LDS, unrolled K, conflict-free swizzle).
//   blocks 4096..8191: Wo transpose+convert (needed only by gemm2) — rides in
//                      gemm1's spare HBM BW (~1.1 of 6 TB/s) and tail CUs.
// ---------------------------------------------------------------------------
__global__ __launch_bounds__(256, 2) void gemm1_kernel(
    const __hip_bfloat16* __restrict__ xhat,
    const __hip_bfloat16* __restrict__ w1t, const __hip_bfloat16* __restrict__ w2t,
    const float* __restrict__ b1, const float* __restrict__ b2,
    const float* __restrict__ b1a, const float* __restrict__ b2a,
    const int* __restrict__ counts, const int* __restrict__ lists,
    __hip_bfloat16* __restrict__ hid,
    const float* __restrict__ Wo, __hip_bfloat16* __restrict__ WoT)
{
    __shared__ __align__(16) char smem[49664];
    const int t = threadIdx.x;

    if (blockIdx.x >= 4096) {
        // ---- Wo transpose branch: R=HH, C=DD, 128x64 tiles ----
        float (*tile)[65] = (float(*)[65])smem;
        const int wb    = blockIdx.x - 4096;   // 0..4095
        const int e     = wb >> 9;
        const int local = wb & 511;
        const int c0    = (local & 15) * 64;
        const int r0    = (local >> 4) * 128;
        const float* src = Wo + (size_t)e * HH * DD + (size_t)r0 * DD + c0;
        __hip_bfloat16* dst = WoT + (size_t)e * HH * DD + (size_t)c0 * HH + r0;

        #pragma unroll
        for (int i = 0; i < 8; i++) {
            const int rr = i * 16 + (t >> 4);
            const int cc = (t & 15) * 4;
            const float4 v = *(const float4*)(src + (size_t)rr * DD + cc);
            tile[rr][cc] = v.x; tile[rr][cc + 1] = v.y;
            tile[rr][cc + 2] = v.z; tile[rr][cc + 3] = v.w;
        }
        __syncthreads();
        #pragma unroll
        for (int i = 0; i < 4; i++) {
            const int id = t + 256 * i;
            const int cc = id >> 4;
            const int rb = (id & 15) * 8;
            union { u16x8 v; __hip_bfloat16 h[8]; } u;
            #pragma unroll
            for (int j = 0; j < 8; j++)
                u.h[j] = __float2bfloat16(tile[rb + j][cc]);
            *(u16x8*)(dst + (size_t)cc * HH + rb) = u.v;
        }
        return;
    }

    // ---- gemm1 branch ----
    __hip_bfloat16* As0  = (__hip_bfloat16*)smem;            // 2 x 4096 elems
    __hip_bfloat16* Bs0  = (__hip_bfloat16*)(smem + 16384);  // 2 x 8192 elems
    int*            toks = (int*)(smem + 49152);             // 128 ints

    const int gid  = blockIdx.x;            // 0..4095
    const int xcd  = gid & 7;
    const int rest = gid >> 3;
    const int m    = rest & 15;
    const int pidx = rest >> 4;
    const int panel = xcd + 8 * pidx;       // 0..255
    const int e   = panel >> 5;
    const int h0  = (panel & 31) * 128;
    const int cnt = counts[e];
    const int m0  = m * 128;
    if (m0 >= cnt) return;
    int base = 0;
    #pragma unroll
    for (int j = 0; j < 8; j++) base += (j < e) ? counts[j] : 0;

    const int lane = t & 63, w = t >> 6;
    const int rsel = lane & 15, crd = lane >> 4;
    const int lr = lane >> 2;
    const int cl = (lane & 3) ^ ((lane >> 3) & 3);
    const int koff = (crd ^ ((rsel >> 1) & 3)) * 8;

    if (t < 128) toks[t] = lists[e * NN + min(m0 + t, cnt - 1)];

    f32x4 acc1[8][2], acc2[8][2];
    const f32x4 z4 = {0.f, 0.f, 0.f, 0.f};
    #pragma unroll
    for (int q = 0; q < 8; q++) {
        acc1[q][0] = z4; acc1[q][1] = z4;
        acc2[q][0] = z4; acc2[q][1] = z4;
    }

    __syncthreads();

    const __hip_bfloat16* pA[2];
    #pragma unroll
    for (int i = 0; i < 2; i++)
        pA[i] = xhat + (size_t)toks[w * 32 + i * 16 + lr] * DD + cl * 8;
    const __hip_bfloat16* pB[4];
    {
        const __hip_bfloat16* wsel = (w < 2) ? w1t : w2t;
        #pragma unroll
        for (int i = 0; i < 4; i++) {
            const int brow = (w & 1) * 64 + i * 16 + lr;
            pB[i] = wsel + ((size_t)e * HH + h0 + brow) * DD + cl * 8;
        }
    }

    auto STAGE = [&](int buf, int ko) {
        #pragma unroll
        for (int i = 0; i < 2; i++)
            __builtin_amdgcn_global_load_lds(AS1P(pA[i] + ko), AS3P(As0 + buf * 4096 + w * 1024 + i * 512), 16, 0, 0);
        #pragma unroll
        for (int i = 0; i < 4; i++)
            __builtin_amdgcn_global_load_lds(AS1P(pB[i] + ko), AS3P(Bs0 + buf * 8192 + w * 2048 + i * 512), 16, 0, 0);
    };
    auto COMPUTE = [&](int buf) {
        const __hip_bfloat16* A = As0 + buf * 4096;
        const __hip_bfloat16* B = Bs0 + buf * 8192;
        bf16x8 af[8], b1q[2], b2q[2];
        #pragma unroll
        for (int mi = 0; mi < 8; mi++)
            af[mi] = *(const bf16x8*)&A[(mi * 16 + rsel) * 32 + koff];
        #pragma unroll
        for (int ni = 0; ni < 2; ni++) {
            b1q[ni] = *(const bf16x8*)&B[(w * 32 + ni * 16 + rsel) * 32 + koff];
            b2q[ni] = *(const bf16x8*)&B[4096 + (w * 32 + ni * 16 + rsel) * 32 + koff];
        }
        __builtin_amdgcn_s_setprio(1);
        #pragma unroll
        for (int mi = 0; mi < 8; mi++)
            #pragma unroll
            for (int ni = 0; ni < 2; ni++) {
                acc1[mi][ni] = mfma16(af[mi], b1q[ni], acc1[mi][ni]);
                acc2[mi][ni] = mfma16(af[mi], b2q[ni], acc2[mi][ni]);
            }
        __builtin_amdgcn_s_setprio(0);
    };

    STAGE(0, 0);
    __syncthreads();
    #pragma unroll
    for (int it = 0; it < 15; ++it) {
        STAGE(1, it * 64 + 32); COMPUTE(0); __syncthreads();
        STAGE(0, it * 64 + 64); COMPUTE(1); __syncthreads();
    }
    STAGE(1, 992); COMPUTE(0); __syncthreads();
    COMPUTE(1);

    const int rq = (lane >> 4) * 4, cq = lane & 15;
    #pragma unroll
    for (int ni = 0; ni < 2; ni++) {
        const int hcol = h0 + w * 32 + ni * 16 + cq;
        const float bb1 = b1[e * HH + hcol] + b1a[e * HH + hcol];
        const float bb2 = b2[e * HH + hcol] + b2a[e * HH + hcol];
        #pragma unroll
        for (int mi = 0; mi < 8; mi++) {
            f32x4 v1 = acc1[mi][ni];
            f32x4 v2 = acc2[mi][ni];
            #pragma unroll
            for (int r = 0; r < 4; r++) {
                const int pos = m0 + mi * 16 + rq + r;
                if (pos < cnt) {
                    float x1 = v1[r] + bb1;
                    float x2 = v2[r] + bb2;
                    x2 = fminf(fmaxf(x2, -20.f), 20.f);
                    float hv = x1 * (x2 / (1.f + __expf(-x2)));
                    hv = fminf(fmaxf(hv, -1e4f), 1e4f);
                    hid[(size_t)(base + pos) * HH + hcol] = __float2bfloat16(hv);
                }
            }
        }
    }
}

// ---------------------------------------------------------------------------
// GEMM2 (R12): split-K=2, BM=128, BN=256, BK=32, 4 waves (pure-N), 48KB LDS.
// Expert = XCD mapping keeps hid (reuse-heavy A operand) L2-local.
// ---------------------------------------------------------------------------
__global__ __launch_bounds__(256, 2) void gemm2_kernel(
    const __hip_bfloat16* __restrict__ hid, const __hip_bfloat16* __restrict__ wot,
    const int* __restrict__ counts, float* __restrict__ P0, float* __restrict__ P1)
{
    const int gid = blockIdx.x;             // 0..1023
    const int e   = gid & 7;                // expert == XCD
    const int k_  = gid >> 3;               // 0..127
    const int m   = k_ & 15;
    const int sp  = (k_ >> 4) & 1;
    const int dp  = k_ >> 5;                // 0..3
    const int d0  = dp * 256;
    const int cnt = counts[e];
    const int m0  = m * 128;
    if (m0 >= cnt) return;
    int base = 0;
    #pragma unroll
    for (int j = 0; j < 8; j++) base += (j < e) ? counts[j] : 0;

    __shared__ __align__(16) __hip_bfloat16 As[2][128 * 32];
    __shared__ __align__(16) __hip_bfloat16 Bs[2][256 * 32];

    const int t = threadIdx.x, lane = t & 63, w = t >> 6;
    const int rsel = lane & 15, crd = lane >> 4;
    const int lr = lane >> 2;
    const int cl = (lane & 3) ^ ((lane >> 3) & 3);
    const int koff = (crd ^ ((rsel >> 1) & 3)) * 8;

    f32x4 acc[8][4];
    const f32x4 z4 = {0.f, 0.f, 0.f, 0.f};
    #pragma unroll
    for (int q = 0; q < 8; q++) {
        acc[q][0] = z4; acc[q][1] = z4; acc[q][2] = z4; acc[q][3] = z4;
    }

    const int kbase = sp * 2048;
    const __hip_bfloat16* pA[2];
    #pragma unroll
    for (int i = 0; i < 2; i++)
        pA[i] = hid + (size_t)(base + min(m0 + w * 32 + i * 16 + lr, cnt - 1)) * HH + kbase + cl * 8;
    const __hip_bfloat16* pB[4];
    #pragma unroll
    for (int i = 0; i < 4; i++)
        pB[i] = wot + ((size_t)e * DD + d0 + w * 64 + i * 16 + lr) * HH + kbase + cl * 8;

    auto STAGE = [&](int buf, int ko) {
        #pragma unroll
        for (int i = 0; i < 2; i++)
            __builtin_amdgcn_global_load_lds(AS1P(pA[i] + ko), AS3P(&As[buf][w * 1024 + i * 512]), 16, 0, 0);
        #pragma unroll
        for (int i = 0; i < 4; i++)
            __builtin_amdgcn_global_load_lds(AS1P(pB[i] + ko), AS3P(&Bs[buf][w * 2048 + i * 512]), 16, 0, 0);
    };
    auto COMPUTE = [&](int buf) {
        bf16x8 af[8], bq[4];
        #pragma unroll
        for (int mi = 0; mi < 8; mi++)
            af[mi] = *(const bf16x8*)&As[buf][(mi * 16 + rsel) * 32 + koff];
        #pragma unroll
        for (int ni = 0; ni < 4; ni++)
            bq[ni] = *(const bf16x8*)&Bs[buf][(w * 64 + ni * 16 + rsel) * 32 + koff];
        __builtin_amdgcn_s_setprio(1);
        #pragma unroll
        for (int mi = 0; mi < 8; mi++)
            #pragma unroll
            for (int ni = 0; ni < 4; ni++)
                acc[mi][ni] = mfma16(af[mi], bq[ni], acc[mi][ni]);
        __builtin_amdgcn_s_setprio(0);
    };

    STAGE(0, 0);
    __syncthreads();
    #pragma unroll
    for (int it = 0; it < 31; ++it) {
        STAGE(1, it * 64 + 32); COMPUTE(0); __syncthreads();
        STAGE(0, it * 64 + 64); COMPUTE(1); __syncthreads();
    }
    STAGE(1, 2016); COMPUTE(0); __syncthreads();
    COMPUTE(1);

    float* dst = sp ? P1 : P0;
    const int rq = (lane >> 4) * 4, cq = lane & 15;
    #pragma unroll
    for (int ni = 0; ni < 4; ni++) {
        const int dcol = d0 + w * 64 + ni * 16 + cq;
        #pragma unroll
        for (int mi = 0; mi < 8; mi++) {
            f32x4 v = acc[mi][ni];
            #pragma unroll
            for (int r = 0; r < 4; r++) {
                const int pos = m0 + mi * 16 + rq + r;
                if (pos < cnt)
                    dst[(size_t)(base + pos) * DD + dcol] = v[r];
            }
        }
    }
}

// ---------------------------------------------------------------------------
// Combine: out[token] = sum_slots gate * clip(P0[slot]+P1[slot]+bo[e], +-1e4)
// ---------------------------------------------------------------------------
__global__ __launch_bounds__(256) void combine_kernel(
    const float* __restrict__ P0, const float* __restrict__ P1,
    const float* __restrict__ bo, const int* __restrict__ counts,
    const int* __restrict__ pairIdx, const float* __restrict__ gates,
    float* __restrict__ out)
{
    const int i = blockIdx.x;
    const int t = threadIdx.x;
    const int s0 = pairIdx[2 * i], s1 = pairIdx[2 * i + 1];
    const int e0 = s0 >> 12, p0 = s0 & (NN - 1);
    const int e1 = s1 >> 12, p1 = s1 & (NN - 1);
    int b0 = 0, b1 = 0;
    #pragma unroll
    for (int j = 0; j < 8; j++) {
        const int c = counts[j];
        b0 += (j < e0) ? c : 0;
        b1 += (j < e1) ? c : 0;
    }
    const float g0 = gates[s0], g1 = gates[s1];
    const size_t r0 = (size_t)(b0 + p0) * DD, r1 = (size_t)(b1 + p1) * DD;
    const float4 a0 = ((const float4*)(P0 + r0))[t], c0 = ((const float4*)(P1 + r0))[t];
    const float4 a1 = ((const float4*)(P0 + r1))[t], c1 = ((const float4*)(P1 + r1))[t];
    const float4 q0 = ((const float4*)(bo + (size_t)e0 * DD))[t];
    const float4 q1 = ((const float4*)(bo + (size_t)e1 * DD))[t];
    float4 r;
    #pragma unroll
    for (int k = 0; k < 4; k++) {
        float v0 = ((const float*)&a0)[k] + ((const float*)&c0)[k] + ((const float*)&q0)[k];
        float v1 = ((const float*)&a1)[k] + ((const float*)&c1)[k] + ((const float*)&q1)[k];
        v0 = fminf(fmaxf(v0, -1e4f), 1e4f);
        v1 = fminf(fmaxf(v1, -1e4f), 1e4f);
        ((float*)&r)[k] = g0 * v0 + g1 * v1;
    }
    ((float4*)(out + (size_t)i * DD))[t] = r;
}

// ---------------------------------------------------------------------------
extern "C" void kernel_launch(void* const* d_in, const int* in_sizes, int n_in,
                              void* d_out, int out_size, void* d_ws, size_t ws_size,
                              hipStream_t stream)
{
    const float* x   = (const float*)d_in[0];
    const float* lng = (const float*)d_in[1];
    const float* lnb = (const float*)d_in[2];
    const float* rw  = (const float*)d_in[3];
    const float* eg  = (const float*)d_in[4];
    const float* eb  = (const float*)d_in[5];
    const float* W1  = (const float*)d_in[6];
    const float* b1  = (const float*)d_in[7];
    const float* W2  = (const float*)d_in[8];
    const float* b2  = (const float*)d_in[9];
    const float* Wo  = (const float*)d_in[10];
    const float* bo  = (const float*)d_in[11];
    float* out = (float*)d_out;

    char* ws = (char*)d_ws;
    const size_t WSZ = (size_t)EE * HH * DD * 2;      // 64MB per weight matrix
    __hip_bfloat16* W1T  = (__hip_bfloat16*)(ws);
    __hip_bfloat16* W2T  = (__hip_bfloat16*)(ws + WSZ);
    __hip_bfloat16* WoT  = (__hip_bfloat16*)(ws + 2 * WSZ);
    __hip_bfloat16* xhat = (__hip_bfloat16*)(ws + 3 * WSZ);
    __hip_bfloat16* hid  = (__hip_bfloat16*)(ws + 3 * WSZ + (size_t)NN * DD * 2);
    char* small = ws + 3 * WSZ + (size_t)NN * DD * 2 + (size_t)2 * NN * HH * 2;
    int*   counts  = (int*)small;
    float* b1a     = (float*)(small + 256);
    float* b2a     = (float*)(small + 256 + 131072);
    int*   lists   = (int*)(small + 256 + 2 * 131072);
    float* gates   = (float*)(small + 256 + 3 * 131072);
    int*   pairIdx = (int*)(small + 256 + 4 * 131072);
    // split-K partials (each 8192x1024 f32 = 32MB) alias W1T / W2T (dead after
    // gemm1; rewritten by prep_kernel at the start of every call).
    float* P0 = (float*)(ws);
    float* P1 = (float*)(ws + WSZ);

    hipMemsetAsync(small, 0, 256 + 2 * 131072, stream);   // counts + b1a + b2a

    prep_kernel<<<12288, 256, 0, stream>>>(
        W1, W2, eg, eb, W1T, W2T, b1a, b2a,
        x, lng, lnb, rw, xhat, counts, lists, gates, pairIdx);

    gemm1_kernel<<<8192, 256, 0, stream>>>(
        xhat, W1T, W2T, b1, b2, b1a, b2a, counts, lists, hid, Wo, WoT);
    gemm2_kernel<<<1024, 256, 0, stream>>>(
        hid, WoT, counts, P0, P1);
    combine_kernel<<<NN, 256, 0, stream>>>(P0, P1, bo, counts, pairIdx, gates, out);
}

// Round 14
// 484.388 us; speedup vs baseline: 1.1706x; 1.0214x over previous
//
#include <hip/hip_runtime.h>
#include <hip/hip_bf16.h>

#define DD 1024
#define HH 4096
#define EE 8
#define NN 4096   // B*T tokens

typedef __attribute__((ext_vector_type(8))) short bf16x8;
typedef __attribute__((ext_vector_type(4))) float f32x4;
typedef __attribute__((ext_vector_type(8))) unsigned short u16x8;

#define AS1P(p) ((__attribute__((address_space(1))) void*)(unsigned long long)(const void*)(p))
#define AS3P(p) ((__attribute__((address_space(3))) void*)(unsigned int)(unsigned long long)(const void*)(p))

__device__ inline f32x4 mfma16(bf16x8 a, bf16x8 b, f32x4 c) {
    return __builtin_amdgcn_mfma_f32_16x16x32_bf16(a, b, c, 0, 0, 0);
}

// ---------------------------------------------------------------------------
// prep_kernel: ONE dispatch fusing
//   blocks 0..8191   : transpose+convert W1 (0..4095) / W2 (4096..8191),
//                      eg-scaled, eb@W accumulated into b1a/b2a.
//   blocks 8192..12287: per-token LN1 -> router -> top2 -> scatter + xhat.
// ---------------------------------------------------------------------------
__global__ __launch_bounds__(256) void prep_kernel(
    const float* __restrict__ W1, const float* __restrict__ W2,
    const float* __restrict__ eg, const float* __restrict__ eb,
    __hip_bfloat16* __restrict__ W1T, __hip_bfloat16* __restrict__ W2T,
    float* __restrict__ b1a, float* __restrict__ b2a,
    const float* __restrict__ x, const float* __restrict__ lng,
    const float* __restrict__ lnb, const float* __restrict__ rw,
    __hip_bfloat16* __restrict__ xhat, int* __restrict__ counts,
    int* __restrict__ lists, float* __restrict__ gates, int* __restrict__ pairIdx)
{
    __shared__ __align__(16) char smem[34304];
    const int bid = blockIdx.x;
    const int t = threadIdx.x;

    if (bid < 8192) {
        float (*tile)[65] = (float(*)[65])smem;          // 128 x 65 x 4B
        float* sg = (float*)(smem + 33280);
        float* sb = sg + 128;
        const int mat   = bid >> 12;                     // 0:W1 1:W2
        const int rem   = bid & 4095;
        const int e     = rem >> 9;
        const int local = rem & 511;
        const int c0    = (local & 63) * 64;
        const int r0    = (local >> 6) * 128;
        const float* src = (mat ? W2 : W1) + (size_t)e * DD * HH + (size_t)r0 * HH + c0;
        __hip_bfloat16* dst = (mat ? W2T : W1T) + (size_t)e * HH * DD + (size_t)c0 * DD + r0;
        float* badd = mat ? b2a : b1a;

        if (t < 128) {
            sg[t] = eg[e * DD + r0 + t];
            sb[t] = eb[e * DD + r0 + t];
        }
        #pragma unroll
        for (int i = 0; i < 8; i++) {
            const int rr = i * 16 + (t >> 4);
            const int cc = (t & 15) * 4;
            const float4 v = *(const float4*)(src + (size_t)rr * HH + cc);
            tile[rr][cc] = v.x; tile[rr][cc + 1] = v.y;
            tile[rr][cc + 2] = v.z; tile[rr][cc + 3] = v.w;
        }
        __syncthreads();

        #pragma unroll
        for (int i = 0; i < 4; i++) {
            const int id = t + 256 * i;
            const int cc = id >> 4;
            const int rb = (id & 15) * 8;
            union { u16x8 v; __hip_bfloat16 h[8]; } u;
            #pragma unroll
            for (int j = 0; j < 8; j++)
                u.h[j] = __float2bfloat16(tile[rb + j][cc] * sg[rb + j]);
            *(u16x8*)(dst + (size_t)cc * DD + rb) = u.v;
        }
        if (t < 64) {
            float sum = 0.f;
            #pragma unroll
            for (int rr = 0; rr < 128; rr++) sum += sb[rr] * tile[rr][t];
            atomicAdd(&badd[e * HH + c0 + t], sum);
        }
        return;
    }

    // ---- token branch ----
    const int i = bid - 8192;
    float* sA = (float*)smem;
    float* sB = sA + 256;
    float* slog = sB + 256;

    float4 xv = ((const float4*)(x + (size_t)i * DD))[t];
    float s1 = xv.x + xv.y + xv.z + xv.w;
    float s2 = xv.x * xv.x + xv.y * xv.y + xv.z * xv.z + xv.w * xv.w;
    sA[t] = s1; sB[t] = s2;
    __syncthreads();
    for (int s = 128; s > 0; s >>= 1) {
        if (t < s) { sA[t] += sA[t + s]; sB[t] += sB[t + s]; }
        __syncthreads();
    }
    const float mu  = sA[0] * (1.0f / DD);
    const float var = sB[0] * (1.0f / DD) - mu * mu;
    const float rstd = rsqrtf(var + 1e-5f);
    __syncthreads();

    float4 gv = ((const float4*)lng)[t];
    float4 bv = ((const float4*)lnb)[t];
    float xf[4];
    xf[0] = (xv.x - mu) * rstd * gv.x + bv.x;
    xf[1] = (xv.y - mu) * rstd * gv.y + bv.y;
    xf[2] = (xv.z - mu) * rstd * gv.z + bv.z;
    xf[3] = (xv.w - mu) * rstd * gv.w + bv.w;

    float lp[8];
    #pragma unroll
    for (int e = 0; e < 8; e++) lp[e] = 0.f;
    {
        const float4* r4 = (const float4*)(rw + (size_t)(t * 4) * EE);
        #pragma unroll
        for (int j = 0; j < 4; j++) {
            float4 ra = r4[j * 2], rb = r4[j * 2 + 1];
            lp[0] += xf[j] * ra.x; lp[1] += xf[j] * ra.y;
            lp[2] += xf[j] * ra.z; lp[3] += xf[j] * ra.w;
            lp[4] += xf[j] * rb.x; lp[5] += xf[j] * rb.y;
            lp[6] += xf[j] * rb.z; lp[7] += xf[j] * rb.w;
        }
    }
    const int lane = t & 63, wid = t >> 6;
    #pragma unroll
    for (int e = 0; e < 8; e++) {
        float v = lp[e];
        #pragma unroll
        for (int o = 32; o > 0; o >>= 1) v += __shfl_down(v, o, 64);
        if (lane == 0) slog[e * 4 + wid] = v;
    }

    s1 = xf[0] + xf[1] + xf[2] + xf[3];
    s2 = xf[0] * xf[0] + xf[1] * xf[1] + xf[2] * xf[2] + xf[3] * xf[3];
    sA[t] = s1; sB[t] = s2;
    __syncthreads();
    for (int s = 128; s > 0; s >>= 1) {
        if (t < s) { sA[t] += sA[t + s]; sB[t] += sB[t + s]; }
        __syncthreads();
    }
    const float mu2  = sA[0] * (1.0f / DD);
    const float var2 = sB[0] * (1.0f / DD) - mu2 * mu2;
    const float rstd2 = rsqrtf(var2 + 1e-5f);

    union { ushort4 v; __hip_bfloat16 h[4]; } u;
    u.h[0] = __float2bfloat16((xf[0] - mu2) * rstd2);
    u.h[1] = __float2bfloat16((xf[1] - mu2) * rstd2);
    u.h[2] = __float2bfloat16((xf[2] - mu2) * rstd2);
    u.h[3] = __float2bfloat16((xf[3] - mu2) * rstd2);
    ((ushort4*)(xhat + (size_t)i * DD))[t] = u.v;

    if (t == 0) {
        float lg[8];
        #pragma unroll
        for (int e = 0; e < 8; e++)
            lg[e] = slog[e * 4] + slog[e * 4 + 1] + slog[e * 4 + 2] + slog[e * 4 + 3];
        int i0 = 0;
        #pragma unroll
        for (int e = 1; e < 8; e++) if (lg[e] > lg[i0]) i0 = e;
        int i1 = (i0 == 0) ? 1 : 0;
        #pragma unroll
        for (int e = 0; e < 8; e++) { if (e != i0 && lg[e] > lg[i1]) i1 = e; }
        const float ex = __expf(lg[i1] - lg[i0]);
        const float g0 = 1.f / (1.f + ex);
        const float g1 = ex / (1.f + ex);
        int p0 = atomicAdd(&counts[i0], 1);
        lists[i0 * NN + p0] = i; gates[i0 * NN + p0] = g0;
        int p1 = atomicAdd(&counts[i1], 1);
        lists[i1 * NN + p1] = i; gates[i1 * NN + p1] = g1;
        pairIdx[2 * i]     = i0 * NN + p0;
        pairIdx[2 * i + 1] = i1 * NN + p1;
    }
}

// ---------------------------------------------------------------------------
// GEMM1 (R8 config) fused with Wo transpose (blocks 4096..8191).
// ---------------------------------------------------------------------------
__global__ __launch_bounds__(256, 2) void gemm1_kernel(
    const __hip_bfloat16* __restrict__ xhat,
    const __hip_bfloat16* __restrict__ w1t, const __hip_bfloat16* __restrict__ w2t,
    const float* __restrict__ b1, const float* __restrict__ b2,
    const float* __restrict__ b1a, const float* __restrict__ b2a,
    const int* __restrict__ counts, const int* __restrict__ lists,
    __hip_bfloat16* __restrict__ hid,
    const float* __restrict__ Wo, __hip_bfloat16* __restrict__ WoT)
{
    __shared__ __align__(16) char smem[49664];
    const int t = threadIdx.x;

    if (blockIdx.x >= 4096) {
        float (*tile)[65] = (float(*)[65])smem;
        const int wb    = blockIdx.x - 4096;
        const int e     = wb >> 9;
        const int local = wb & 511;
        const int c0    = (local & 15) * 64;
        const int r0    = (local >> 4) * 128;
        const float* src = Wo + (size_t)e * HH * DD + (size_t)r0 * DD + c0;
        __hip_bfloat16* dst = WoT + (size_t)e * HH * DD + (size_t)c0 * HH + r0;

        #pragma unroll
        for (int i = 0; i < 8; i++) {
            const int rr = i * 16 + (t >> 4);
            const int cc = (t & 15) * 4;
            const float4 v = *(const float4*)(src + (size_t)rr * DD + cc);
            tile[rr][cc] = v.x; tile[rr][cc + 1] = v.y;
            tile[rr][cc + 2] = v.z; tile[rr][cc + 3] = v.w;
        }
        __syncthreads();
        #pragma unroll
        for (int i = 0; i < 4; i++) {
            const int id = t + 256 * i;
            const int cc = id >> 4;
            const int rb = (id & 15) * 8;
            union { u16x8 v; __hip_bfloat16 h[8]; } u;
            #pragma unroll
            for (int j = 0; j < 8; j++)
                u.h[j] = __float2bfloat16(tile[rb + j][cc]);
            *(u16x8*)(dst + (size_t)cc * HH + rb) = u.v;
        }
        return;
    }

    __hip_bfloat16* As0  = (__hip_bfloat16*)smem;
    __hip_bfloat16* Bs0  = (__hip_bfloat16*)(smem + 16384);
    int*            toks = (int*)(smem + 49152);

    const int gid  = blockIdx.x;
    const int xcd  = gid & 7;
    const int rest = gid >> 3;
    const int m    = rest & 15;
    const int pidx = rest >> 4;
    const int panel = xcd + 8 * pidx;
    const int e   = panel >> 5;
    const int h0  = (panel & 31) * 128;
    const int cnt = counts[e];
    const int m0  = m * 128;
    if (m0 >= cnt) return;
    int base = 0;
    #pragma unroll
    for (int j = 0; j < 8; j++) base += (j < e) ? counts[j] : 0;

    const int lane = t & 63, w = t >> 6;
    const int rsel = lane & 15, crd = lane >> 4;
    const int lr = lane >> 2;
    const int cl = (lane & 3) ^ ((lane >> 3) & 3);
    const int koff = (crd ^ ((rsel >> 1) & 3)) * 8;

    if (t < 128) toks[t] = lists[e * NN + min(m0 + t, cnt - 1)];

    f32x4 acc1[8][2], acc2[8][2];
    const f32x4 z4 = {0.f, 0.f, 0.f, 0.f};
    #pragma unroll
    for (int q = 0; q < 8; q++) {
        acc1[q][0] = z4; acc1[q][1] = z4;
        acc2[q][0] = z4; acc2[q][1] = z4;
    }

    __syncthreads();

    const __hip_bfloat16* pA[2];
    #pragma unroll
    for (int i = 0; i < 2; i++)
        pA[i] = xhat + (size_t)toks[w * 32 + i * 16 + lr] * DD + cl * 8;
    const __hip_bfloat16* pB[4];
    {
        const __hip_bfloat16* wsel = (w < 2) ? w1t : w2t;
        #pragma unroll
        for (int i = 0; i < 4; i++) {
            const int brow = (w & 1) * 64 + i * 16 + lr;
            pB[i] = wsel + ((size_t)e * HH + h0 + brow) * DD + cl * 8;
        }
    }

    auto STAGE = [&](int buf, int ko) {
        #pragma unroll
        for (int i = 0; i < 2; i++)
            __builtin_amdgcn_global_load_lds(AS1P(pA[i] + ko), AS3P(As0 + buf * 4096 + w * 1024 + i * 512), 16, 0, 0);
        #pragma unroll
        for (int i = 0; i < 4; i++)
            __builtin_amdgcn_global_load_lds(AS1P(pB[i] + ko), AS3P(Bs0 + buf * 8192 + w * 2048 + i * 512), 16, 0, 0);
    };
    auto COMPUTE = [&](int buf) {
        const __hip_bfloat16* A = As0 + buf * 4096;
        const __hip_bfloat16* B = Bs0 + buf * 8192;
        bf16x8 af[8], b1q[2], b2q[2];
        #pragma unroll
        for (int mi = 0; mi < 8; mi++)
            af[mi] = *(const bf16x8*)&A[(mi * 16 + rsel) * 32 + koff];
        #pragma unroll
        for (int ni = 0; ni < 2; ni++) {
            b1q[ni] = *(const bf16x8*)&B[(w * 32 + ni * 16 + rsel) * 32 + koff];
            b2q[ni] = *(const bf16x8*)&B[4096 + (w * 32 + ni * 16 + rsel) * 32 + koff];
        }
        __builtin_amdgcn_s_setprio(1);
        #pragma unroll
        for (int mi = 0; mi < 8; mi++)
            #pragma unroll
            for (int ni = 0; ni < 2; ni++) {
                acc1[mi][ni] = mfma16(af[mi], b1q[ni], acc1[mi][ni]);
                acc2[mi][ni] = mfma16(af[mi], b2q[ni], acc2[mi][ni]);
            }
        __builtin_amdgcn_s_setprio(0);
    };

    STAGE(0, 0);
    __syncthreads();
    #pragma unroll
    for (int it = 0; it < 15; ++it) {
        STAGE(1, it * 64 + 32); COMPUTE(0); __syncthreads();
        STAGE(0, it * 64 + 64); COMPUTE(1); __syncthreads();
    }
    STAGE(1, 992); COMPUTE(0); __syncthreads();
    COMPUTE(1);

    const int rq = (lane >> 4) * 4, cq = lane & 15;
    #pragma unroll
    for (int ni = 0; ni < 2; ni++) {
        const int hcol = h0 + w * 32 + ni * 16 + cq;
        const float bb1 = b1[e * HH + hcol] + b1a[e * HH + hcol];
        const float bb2 = b2[e * HH + hcol] + b2a[e * HH + hcol];
        #pragma unroll
        for (int mi = 0; mi < 8; mi++) {
            f32x4 v1 = acc1[mi][ni];
            f32x4 v2 = acc2[mi][ni];
            #pragma unroll
            for (int r = 0; r < 4; r++) {
                const int pos = m0 + mi * 16 + rq + r;
                if (pos < cnt) {
                    float x1 = v1[r] + bb1;
                    float x2 = v2[r] + bb2;
                    x2 = fminf(fmaxf(x2, -20.f), 20.f);
                    float hv = x1 * (x2 / (1.f + __expf(-x2)));
                    hv = fminf(fmaxf(hv, -1e4f), 1e4f);
                    hid[(size_t)(base + pos) * HH + hcol] = __float2bfloat16(hv);
                }
            }
        }
    }
}

// ---------------------------------------------------------------------------
// GEMM2: split-K=2, BM=128, BN=256, expert=XCD mapping; partials in BF16
// (halves P round-trip traffic; precision margin audited: +~0.004 abs).
// ---------------------------------------------------------------------------
__global__ __launch_bounds__(256, 2) void gemm2_kernel(
    const __hip_bfloat16* __restrict__ hid, const __hip_bfloat16* __restrict__ wot,
    const int* __restrict__ counts, __hip_bfloat16* __restrict__ P0,
    __hip_bfloat16* __restrict__ P1)
{
    const int gid = blockIdx.x;             // 0..1023
    const int e   = gid & 7;                // expert == XCD
    const int k_  = gid >> 3;
    const int m   = k_ & 15;
    const int sp  = (k_ >> 4) & 1;
    const int dp  = k_ >> 5;
    const int d0  = dp * 256;
    const int cnt = counts[e];
    const int m0  = m * 128;
    if (m0 >= cnt) return;
    int base = 0;
    #pragma unroll
    for (int j = 0; j < 8; j++) base += (j < e) ? counts[j] : 0;

    __shared__ __align__(16) __hip_bfloat16 As[2][128 * 32];
    __shared__ __align__(16) __hip_bfloat16 Bs[2][256 * 32];

    const int t = threadIdx.x, lane = t & 63, w = t >> 6;
    const int rsel = lane & 15, crd = lane >> 4;
    const int lr = lane >> 2;
    const int cl = (lane & 3) ^ ((lane >> 3) & 3);
    const int koff = (crd ^ ((rsel >> 1) & 3)) * 8;

    f32x4 acc[8][4];
    const f32x4 z4 = {0.f, 0.f, 0.f, 0.f};
    #pragma unroll
    for (int q = 0; q < 8; q++) {
        acc[q][0] = z4; acc[q][1] = z4; acc[q][2] = z4; acc[q][3] = z4;
    }

    const int kbase = sp * 2048;
    const __hip_bfloat16* pA[2];
    #pragma unroll
    for (int i = 0; i < 2; i++)
        pA[i] = hid + (size_t)(base + min(m0 + w * 32 + i * 16 + lr, cnt - 1)) * HH + kbase + cl * 8;
    const __hip_bfloat16* pB[4];
    #pragma unroll
    for (int i = 0; i < 4; i++)
        pB[i] = wot + ((size_t)e * DD + d0 + w * 64 + i * 16 + lr) * HH + kbase + cl * 8;

    auto STAGE = [&](int buf, int ko) {
        #pragma unroll
        for (int i = 0; i < 2; i++)
            __builtin_amdgcn_global_load_lds(AS1P(pA[i] + ko), AS3P(&As[buf][w * 1024 + i * 512]), 16, 0, 0);
        #pragma unroll
        for (int i = 0; i < 4; i++)
            __builtin_amdgcn_global_load_lds(AS1P(pB[i] + ko), AS3P(&Bs[buf][w * 2048 + i * 512]), 16, 0, 0);
    };
    auto COMPUTE = [&](int buf) {
        bf16x8 af[8], bq[4];
        #pragma unroll
        for (int mi = 0; mi < 8; mi++)
            af[mi] = *(const bf16x8*)&As[buf][(mi * 16 + rsel) * 32 + koff];
        #pragma unroll
        for (int ni = 0; ni < 4; ni++)
            bq[ni] = *(const bf16x8*)&Bs[buf][(w * 64 + ni * 16 + rsel) * 32 + koff];
        __builtin_amdgcn_s_setprio(1);
        #pragma unroll
        for (int mi = 0; mi < 8; mi++)
            #pragma unroll
            for (int ni = 0; ni < 4; ni++)
                acc[mi][ni] = mfma16(af[mi], bq[ni], acc[mi][ni]);
        __builtin_amdgcn_s_setprio(0);
    };

    STAGE(0, 0);
    __syncthreads();
    #pragma unroll
    for (int it = 0; it < 31; ++it) {
        STAGE(1, it * 64 + 32); COMPUTE(0); __syncthreads();
        STAGE(0, it * 64 + 64); COMPUTE(1); __syncthreads();
    }
    STAGE(1, 2016); COMPUTE(0); __syncthreads();
    COMPUTE(1);

    __hip_bfloat16* dst = sp ? P1 : P0;
    const int rq = (lane >> 4) * 4, cq = lane & 15;
    #pragma unroll
    for (int ni = 0; ni < 4; ni++) {
        const int dcol = d0 + w * 64 + ni * 16 + cq;
        #pragma unroll
        for (int mi = 0; mi < 8; mi++) {
            f32x4 v = acc[mi][ni];
            #pragma unroll
            for (int r = 0; r < 4; r++) {
                const int pos = m0 + mi * 16 + rq + r;
                if (pos < cnt)
                    dst[(size_t)(base + pos) * DD + dcol] = __float2bfloat16(v[r]);
            }
        }
    }
}

// ---------------------------------------------------------------------------
// Combine: out[token] = sum_slots gate * clip(P0[slot]+P1[slot]+bo[e], +-1e4)
// P0/P1 are bf16.
// ---------------------------------------------------------------------------
__global__ __launch_bounds__(256) void combine_kernel(
    const __hip_bfloat16* __restrict__ P0, const __hip_bfloat16* __restrict__ P1,
    const float* __restrict__ bo, const int* __restrict__ counts,
    const int* __restrict__ pairIdx, const float* __restrict__ gates,
    float* __restrict__ out)
{
    const int i = blockIdx.x;
    const int t = threadIdx.x;
    const int s0 = pairIdx[2 * i], s1 = pairIdx[2 * i + 1];
    const int e0 = s0 >> 12, p0 = s0 & (NN - 1);
    const int e1 = s1 >> 12, p1 = s1 & (NN - 1);
    int b0 = 0, b1 = 0;
    #pragma unroll
    for (int j = 0; j < 8; j++) {
        const int c = counts[j];
        b0 += (j < e0) ? c : 0;
        b1 += (j < e1) ? c : 0;
    }
    const float g0 = gates[s0], g1 = gates[s1];
    const size_t r0 = (size_t)(b0 + p0) * DD + t * 4;
    const size_t r1 = (size_t)(b1 + p1) * DD + t * 4;
    union { ushort4 v; __hip_bfloat16 h[4]; } a0, c0u, a1, c1u;
    a0.v  = *(const ushort4*)(P0 + r0);
    c0u.v = *(const ushort4*)(P1 + r0);
    a1.v  = *(const ushort4*)(P0 + r1);
    c1u.v = *(const ushort4*)(P1 + r1);
    const float4 q0 = ((const float4*)(bo + (size_t)e0 * DD))[t];
    const float4 q1 = ((const float4*)(bo + (size_t)e1 * DD))[t];
    float4 r;
    #pragma unroll
    for (int k = 0; k < 4; k++) {
        float v0 = __bfloat162float(a0.h[k]) + __bfloat162float(c0u.h[k]) + ((const float*)&q0)[k];
        float v1 = __bfloat162float(a1.h[k]) + __bfloat162float(c1u.h[k]) + ((const float*)&q1)[k];
        v0 = fminf(fmaxf(v0, -1e4f), 1e4f);
        v1 = fminf(fmaxf(v1, -1e4f), 1e4f);
        ((float*)&r)[k] = g0 * v0 + g1 * v1;
    }
    ((float4*)(out + (size_t)i * DD))[t] = r;
}

// ---------------------------------------------------------------------------
extern "C" void kernel_launch(void* const* d_in, const int* in_sizes, int n_in,
                              void* d_out, int out_size, void* d_ws, size_t ws_size,
                              hipStream_t stream)
{
    const float* x   = (const float*)d_in[0];
    const float* lng = (const float*)d_in[1];
    const float* lnb = (const float*)d_in[2];
    const float* rw  = (const float*)d_in[3];
    const float* eg  = (const float*)d_in[4];
    const float* eb  = (const float*)d_in[5];
    const float* W1  = (const float*)d_in[6];
    const float* b1  = (const float*)d_in[7];
    const float* W2  = (const float*)d_in[8];
    const float* b2  = (const float*)d_in[9];
    const float* Wo  = (const float*)d_in[10];
    const float* bo  = (const float*)d_in[11];
    float* out = (float*)d_out;

    char* ws = (char*)d_ws;
    const size_t WSZ = (size_t)EE * HH * DD * 2;      // 64MB per weight matrix
    __hip_bfloat16* W1T  = (__hip_bfloat16*)(ws);
    __hip_bfloat16* W2T  = (__hip_bfloat16*)(ws + WSZ);
    __hip_bfloat16* WoT  = (__hip_bfloat16*)(ws + 2 * WSZ);
    __hip_bfloat16* xhat = (__hip_bfloat16*)(ws + 3 * WSZ);
    __hip_bfloat16* hid  = (__hip_bfloat16*)(ws + 3 * WSZ + (size_t)NN * DD * 2);
    char* small = ws + 3 * WSZ + (size_t)NN * DD * 2 + (size_t)2 * NN * HH * 2;
    int*   counts  = (int*)small;
    float* b1a     = (float*)(small + 256);
    float* b2a     = (float*)(small + 256 + 131072);
    int*   lists   = (int*)(small + 256 + 2 * 131072);
    float* gates   = (float*)(small + 256 + 3 * 131072);
    int*   pairIdx = (int*)(small + 256 + 4 * 131072);
    // bf16 split-K partials (each 8192x1024 bf16 = 16MB) alias W1T (dead after
    // gemm1; rewritten by prep_kernel at the start of every call).
    __hip_bfloat16* P0 = (__hip_bfloat16*)(ws);
    __hip_bfloat16* P1 = (__hip_bfloat16*)(ws + WSZ / 2);

    hipMemsetAsync(small, 0, 256 + 2 * 131072, stream);   // counts + b1a + b2a

    prep_kernel<<<12288, 256, 0, stream>>>(
        W1, W2, eg, eb, W1T, W2T, b1a, b2a,
        x, lng, lnb, rw, xhat, counts, lists, gates, pairIdx);

    gemm1_kernel<<<8192, 256, 0, stream>>>(
        xhat, W1T, W2T, b1, b2, b1a, b2a, counts, lists, hid, Wo, WoT);
    gemm2_kernel<<<1024, 256, 0, stream>>>(
        hid, WoT, counts, P0, P1);
    combine_kernel<<<NN, 256, 0, stream>>>(P0, P1, bo, counts, pairIdx, gates, out);
}